// Round 1
// baseline (1923.474 us; speedup 1.0000x reference)
//
#include <hip/hip_runtime.h>
#include <hip/hip_bf16.h>
#include <cstdint>

// ---- problem constants (HierarchicalBrainGNN) ----
constexpr int NN   = 20000;          // nodes
constexpr int NE   = 320000;         // edges before self loops
constexpr int ETOT = NE + NN;        // with self loops
constexpr int BG   = 8;              // graphs
constexpr int FIN  = 100;
constexpr int HID  = 256;
constexpr int H    = 4;              // heads
constexpr float SLOPE  = 0.2f;
constexpr float LN_EPS = 1e-5f;

#define DEVFN __device__ __forceinline__

DEVFN float lrelu(float v) { return v > 0.f ? v : SLOPE * v; }
// monotone float<->uint encoding for atomicMax over signed floats
DEVFN unsigned encf(float f) {
    unsigned u = __float_as_uint(f);
    return (u & 0x80000000u) ? ~u : (u | 0x80000000u);
}
DEVFN float decf(unsigned u) {
    return (u & 0x80000000u) ? __uint_as_float(u & 0x7fffffffu) : __uint_as_float(~u);
}

// ---------------- utility ----------------
__global__ void zero_u32(uint32_t* __restrict__ p, int n) {
    int i = blockIdx.x * blockDim.x + threadIdx.x;
    if (i < n) p[i] = 0u;
}

// ---------------- CSR build ----------------
__global__ void count_deg(const int* __restrict__ ei, int* __restrict__ deg) {
    int k = blockIdx.x * blockDim.x + threadIdx.x;
    if (k >= ETOT) return;
    int d = (k < NE) ? ei[NE + k] : (k - NE);
    atomicAdd(&deg[d], 1);
}

__global__ void scan_kernel(const int* __restrict__ deg, int* __restrict__ rowptr) {
    __shared__ int buf[1024];
    int carry = 0;
    for (int base = 0; base < NN; base += 1024) {
        int i = base + threadIdx.x;
        int v = (i < NN) ? deg[i] : 0;
        buf[threadIdx.x] = v;
        __syncthreads();
        for (int off = 1; off < 1024; off <<= 1) {
            int t = (threadIdx.x >= off) ? buf[threadIdx.x - off] : 0;
            __syncthreads();
            buf[threadIdx.x] += t;
            __syncthreads();
        }
        int incl = buf[threadIdx.x];
        if (i < NN) rowptr[i] = carry + incl - v;   // exclusive prefix
        int total = buf[1023];
        __syncthreads();
        carry += total;
    }
    if (threadIdx.x == 0) rowptr[NN] = carry;
}

__global__ void scatter_edges(const int* __restrict__ ei, const int* __restrict__ rowptr,
                              int* __restrict__ fill, int* __restrict__ esrc,
                              int* __restrict__ edst) {
    int k = blockIdx.x * blockDim.x + threadIdx.x;
    if (k >= ETOT) return;
    int s, d;
    if (k < NE) { s = ei[k]; d = ei[NE + k]; }
    else        { s = k - NE; d = k - NE; }
    int pos = rowptr[d] + atomicAdd(&fill[d], 1);
    esrc[pos] = s;
    edst[pos] = d;
}

// ---------------- GEMM: C[M,NC] = A[M,K] @ W[K,NC] (+bias)(+relu) ----------------
template <int K, int NC, int TM, bool RELU, bool BIAS>
__global__ void gemm_rows(const float* __restrict__ A, const float* __restrict__ W,
                          const float* __restrict__ bias, float* __restrict__ C, int M) {
    __shared__ float As[TM][K];
    int row0 = blockIdx.x * TM;
    for (int idx = threadIdx.x; idx < TM * K; idx += blockDim.x) {
        int r = idx / K, k = idx - r * K;
        int gr = row0 + r;
        As[r][k] = (gr < M) ? A[(size_t)gr * K + k] : 0.f;
    }
    __syncthreads();
    for (int c = threadIdx.x; c < NC; c += blockDim.x) {
        float acc[TM];
#pragma unroll
        for (int r = 0; r < TM; r++) acc[r] = 0.f;
        for (int k = 0; k < K; k++) {
            float w = W[(size_t)k * NC + c];
#pragma unroll
            for (int r = 0; r < TM; r++) acc[r] += As[r][k] * w;
        }
        float bv = BIAS ? bias[c] : 0.f;
#pragma unroll
        for (int r = 0; r < TM; r++) {
            int gr = row0 + r;
            if (gr < M) {
                float v = acc[r] + bv;
                if (RELU) v = fmaxf(v, 0.f);
                C[(size_t)gr * NC + c] = v;
            }
        }
    }
}

// ---------------- attention logits: al_s/al_d [N,H] ----------------
template <int DO>
__global__ void compute_al(const float* __restrict__ hproj, const float* __restrict__ a_s,
                           const float* __restrict__ a_d, float* __restrict__ al_s,
                           float* __restrict__ al_d) {
    int n = blockIdx.x;
    int head = threadIdx.x >> 6;   // 4 waves, one head each
    int lane = threadIdx.x & 63;
    const float* hp = hproj + (size_t)n * H * DO + head * DO;
    float ss = 0.f, sd = 0.f;
    for (int c = lane; c < DO; c += 64) {
        float v = hp[c];
        ss += v * a_s[head * DO + c];
        sd += v * a_d[head * DO + c];
    }
#pragma unroll
    for (int off = 32; off > 0; off >>= 1) {
        ss += __shfl_down(ss, off);
        sd += __shfl_down(sd, off);
    }
    if (lane == 0) {
        al_s[n * H + head] = ss;
        al_d[n * H + head] = sd;
    }
}

// ---------------- edge passes ----------------
__global__ void edge_max(const int* __restrict__ esrc, const int* __restrict__ edst,
                         const float* __restrict__ al_s, const float* __restrict__ al_d,
                         float* __restrict__ earr, unsigned* __restrict__ menc) {
    int p = blockIdx.x * blockDim.x + threadIdx.x;
    if (p >= ETOT) return;
    int s = esrc[p], d = edst[p];
    float4 s4 = *(const float4*)(al_s + 4 * (size_t)s);
    float4 d4 = *(const float4*)(al_d + 4 * (size_t)d);
    float e0 = lrelu(s4.x + d4.x);
    float e1 = lrelu(s4.y + d4.y);
    float e2 = lrelu(s4.z + d4.z);
    float e3 = lrelu(s4.w + d4.w);
    ((float4*)earr)[p] = make_float4(e0, e1, e2, e3);
    atomicMax(&menc[4 * d + 0], encf(e0));
    atomicMax(&menc[4 * d + 1], encf(e1));
    atomicMax(&menc[4 * d + 2], encf(e2));
    atomicMax(&menc[4 * d + 3], encf(e3));
}

__global__ void edge_exp(const int* __restrict__ edst, float* __restrict__ earr,
                         const unsigned* __restrict__ menc, float* __restrict__ den) {
    int p = blockIdx.x * blockDim.x + threadIdx.x;
    if (p >= ETOT) return;
    int d = edst[p];
    float4 e = ((const float4*)earr)[p];
    float x0 = expf(e.x - decf(menc[4 * d + 0]));
    float x1 = expf(e.y - decf(menc[4 * d + 1]));
    float x2 = expf(e.z - decf(menc[4 * d + 2]));
    float x3 = expf(e.w - decf(menc[4 * d + 3]));
    ((float4*)earr)[p] = make_float4(x0, x1, x2, x3);
    atomicAdd(&den[4 * d + 0], x0);
    atomicAdd(&den[4 * d + 1], x1);
    atomicAdd(&den[4 * d + 2], x2);
    atomicAdd(&den[4 * d + 3], x3);
}

// ---------------- aggregate + head-mean + bias + relu + LN (+residual) ----------------
template <int DO, bool RESID>
__global__ void aggregate(const float* __restrict__ hproj, const int* __restrict__ rowptr,
                          const int* __restrict__ esrc, const float* __restrict__ earr,
                          const float* __restrict__ den, const float* __restrict__ bias,
                          const float* __restrict__ gamma, const float* __restrict__ beta,
                          const float* __restrict__ hprev, float* __restrict__ hout) {
    constexpr int BD = (DO < 64) ? 64 : DO;
    __shared__ float red[BD];
    int n = blockIdx.x;
    int c = threadIdx.x;

    float4 dn = *(const float4*)(den + 4 * (size_t)n);
    float i0 = 1.f / (dn.x + 1e-16f);
    float i1 = 1.f / (dn.y + 1e-16f);
    float i2 = 1.f / (dn.z + 1e-16f);
    float i3 = 1.f / (dn.w + 1e-16f);

    float a0 = 0.f, a1 = 0.f, a2 = 0.f, a3 = 0.f;
    int p0 = rowptr[n], p1 = rowptr[n + 1];
    for (int p = p0; p < p1; p++) {
        int s = esrc[p];
        float4 ex = ((const float4*)earr)[p];
        if (c < DO) {
            const float* hp = hproj + (size_t)s * (H * DO);
            a0 += (ex.x * i0) * hp[c];
            a1 += (ex.y * i1) * hp[DO + c];
            a2 += (ex.z * i2) * hp[2 * DO + c];
            a3 += (ex.w * i3) * hp[3 * DO + c];
        }
    }
    float val = 0.f;
    if (c < DO) {
        val = 0.25f * (a0 + a1 + a2 + a3) + bias[c];
        val = fmaxf(val, 0.f);   // relu before LN
    }
    // LayerNorm over DO channels
    red[threadIdx.x] = (c < DO) ? val : 0.f;
    __syncthreads();
    for (int off = BD / 2; off > 0; off >>= 1) {
        if (threadIdx.x < off) red[threadIdx.x] += red[threadIdx.x + off];
        __syncthreads();
    }
    float mu = red[0] / DO;
    __syncthreads();
    float dv = (c < DO) ? (val - mu) : 0.f;
    red[threadIdx.x] = dv * dv;
    __syncthreads();
    for (int off = BD / 2; off > 0; off >>= 1) {
        if (threadIdx.x < off) red[threadIdx.x] += red[threadIdx.x + off];
        __syncthreads();
    }
    float var = red[0] / DO;
    if (c < DO) {
        float o = dv * rsqrtf(var + LN_EPS) * gamma[c] + beta[c];
        if (RESID) o += hprev[(size_t)n * DO + c];
        hout[(size_t)n * DO + c] = o;
    }
}

// ---------------- pooling + readout ----------------
__global__ void pool_accum(const float* __restrict__ h, const int* __restrict__ batch,
                           float* __restrict__ pooled, float* __restrict__ cnt) {
    int idx = blockIdx.x * blockDim.x + threadIdx.x;
    if (idx >= NN * 32) return;
    int n = idx >> 5, c = idx & 31;
    int b = batch[n];
    atomicAdd(&pooled[b * 32 + c], h[idx]);
    if (c == 0) atomicAdd(&cnt[b], 1.f);
}

__global__ void final_out(const float* __restrict__ pooled, const float* __restrict__ cnt,
                          const float* __restrict__ Wo, const float* __restrict__ bo,
                          float* __restrict__ out) {
    int b = threadIdx.x;
    if (b < BG) {
        float inv = 1.f / fmaxf(cnt[b], 1.f);
        float acc = 0.f;
        for (int c = 0; c < 32; c++) acc += pooled[b * 32 + c] * inv * Wo[c];
        out[b] = acc + bo[0];
    }
}

// ---------------- host orchestration ----------------
extern "C" void kernel_launch(void* const* d_in, const int* in_sizes, int n_in,
                              void* d_out, int out_size, void* d_ws, size_t ws_size,
                              hipStream_t stream) {
    const float* x     = (const float*)d_in[0];
    const int*   ei    = (const int*)d_in[1];
    const int*   batch = (const int*)d_in[2];
    const float* Wi    = (const float*)d_in[3];
    const float* bi    = (const float*)d_in[4];
    const float* Wl[4]  = {(const float*)d_in[5],  (const float*)d_in[11], (const float*)d_in[17], (const float*)d_in[23]};
    const float* Asl[4] = {(const float*)d_in[6],  (const float*)d_in[12], (const float*)d_in[18], (const float*)d_in[24]};
    const float* Adl[4] = {(const float*)d_in[7],  (const float*)d_in[13], (const float*)d_in[19], (const float*)d_in[25]};
    const float* Bl[4]  = {(const float*)d_in[8],  (const float*)d_in[14], (const float*)d_in[20], (const float*)d_in[26]};
    const float* Gl[4]  = {(const float*)d_in[9],  (const float*)d_in[15], (const float*)d_in[21], (const float*)d_in[27]};
    const float* Bel[4] = {(const float*)d_in[10], (const float*)d_in[16], (const float*)d_in[22], (const float*)d_in[28]};
    const float* Wo = (const float*)d_in[29];
    const float* bo = (const float*)d_in[30];

    char* p = (char*)d_ws;
    auto take = [&](size_t bytes) -> void* {
        void* r = (void*)p;
        p += (bytes + 255) & ~(size_t)255;
        return r;
    };
    float*    hA     = (float*)take((size_t)NN * HID * 4);
    float*    hB     = (float*)take((size_t)NN * HID * 4);
    float*    hproj  = (float*)take((size_t)NN * H * HID * 4);
    float*    al_s   = (float*)take((size_t)NN * H * 4);
    float*    al_d   = (float*)take((size_t)NN * H * 4);
    unsigned* menc   = (unsigned*)take((size_t)NN * H * 4);  // adjacent to den
    float*    den    = (float*)take((size_t)NN * H * 4);
    float*    earr   = (float*)take((size_t)ETOT * H * 4);
    int*      deg    = (int*)take((size_t)NN * 4);
    int*      fill   = (int*)take((size_t)NN * 4);
    int*      rowptr = (int*)take((size_t)(NN + 1) * 4);
    int*      esrc   = (int*)take((size_t)ETOT * 4);
    int*      edst   = (int*)take((size_t)ETOT * 4);
    float*    pooled = (float*)take((size_t)BG * 32 * 4);   // adjacent to cnt
    float*    cnt    = (float*)take((size_t)BG * 4);
    (void)ws_size; (void)n_in; (void)in_sizes; (void)out_size; (void)cnt;

    const int ZB = 256;
    const int egrid = (ETOT + ZB - 1) / ZB;
    const int ggrid = (NN + 7) / 8;

    // zero: deg, fill, pooled+cnt
    zero_u32<<<(NN + ZB - 1) / ZB, ZB, 0, stream>>>((uint32_t*)deg, NN);
    zero_u32<<<(NN + ZB - 1) / ZB, ZB, 0, stream>>>((uint32_t*)fill, NN);
    zero_u32<<<1, ZB, 0, stream>>>((uint32_t*)pooled, BG * 32 + BG + 56); // pooled pad + cnt

    // CSR by dst
    count_deg<<<egrid, ZB, 0, stream>>>(ei, deg);
    scan_kernel<<<1, 1024, 0, stream>>>(deg, rowptr);
    scatter_edges<<<egrid, ZB, 0, stream>>>(ei, rowptr, fill, esrc, edst);

    // input layer: hA = relu(x @ Wi + bi)
    gemm_rows<FIN, HID, 8, true, true><<<ggrid, 256, 0, stream>>>(x, Wi, bi, hA, NN);

    // ---- level 0: 256 -> 256, residual ----
    gemm_rows<256, 1024, 8, false, false><<<ggrid, 256, 0, stream>>>(hA, Wl[0], nullptr, hproj, NN);
    compute_al<256><<<NN, 256, 0, stream>>>(hproj, Asl[0], Adl[0], al_s, al_d);
    zero_u32<<<(2 * NN * H + ZB - 1) / ZB, ZB, 0, stream>>>((uint32_t*)menc, 2 * NN * H);
    edge_max<<<egrid, ZB, 0, stream>>>(esrc, edst, al_s, al_d, earr, menc);
    edge_exp<<<egrid, ZB, 0, stream>>>(edst, earr, menc, den);
    aggregate<256, true><<<NN, 256, 0, stream>>>(hproj, rowptr, esrc, earr, den,
                                                 Bl[0], Gl[0], Bel[0], hA, hB);
    // ---- level 1: 256 -> 128 ----
    gemm_rows<256, 512, 8, false, false><<<ggrid, 256, 0, stream>>>(hB, Wl[1], nullptr, hproj, NN);
    compute_al<128><<<NN, 256, 0, stream>>>(hproj, Asl[1], Adl[1], al_s, al_d);
    zero_u32<<<(2 * NN * H + ZB - 1) / ZB, ZB, 0, stream>>>((uint32_t*)menc, 2 * NN * H);
    edge_max<<<egrid, ZB, 0, stream>>>(esrc, edst, al_s, al_d, earr, menc);
    edge_exp<<<egrid, ZB, 0, stream>>>(edst, earr, menc, den);
    aggregate<128, false><<<NN, 128, 0, stream>>>(hproj, rowptr, esrc, earr, den,
                                                  Bl[1], Gl[1], Bel[1], nullptr, hA);
    // ---- level 2: 128 -> 64 ----
    gemm_rows<128, 256, 8, false, false><<<ggrid, 256, 0, stream>>>(hA, Wl[2], nullptr, hproj, NN);
    compute_al<64><<<NN, 256, 0, stream>>>(hproj, Asl[2], Adl[2], al_s, al_d);
    zero_u32<<<(2 * NN * H + ZB - 1) / ZB, ZB, 0, stream>>>((uint32_t*)menc, 2 * NN * H);
    edge_max<<<egrid, ZB, 0, stream>>>(esrc, edst, al_s, al_d, earr, menc);
    edge_exp<<<egrid, ZB, 0, stream>>>(edst, earr, menc, den);
    aggregate<64, false><<<NN, 64, 0, stream>>>(hproj, rowptr, esrc, earr, den,
                                                Bl[2], Gl[2], Bel[2], nullptr, hB);
    // ---- level 3: 64 -> 32 ----
    gemm_rows<64, 128, 8, false, false><<<ggrid, 128, 0, stream>>>(hB, Wl[3], nullptr, hproj, NN);
    compute_al<32><<<NN, 256, 0, stream>>>(hproj, Asl[3], Adl[3], al_s, al_d);
    zero_u32<<<(2 * NN * H + ZB - 1) / ZB, ZB, 0, stream>>>((uint32_t*)menc, 2 * NN * H);
    edge_max<<<egrid, ZB, 0, stream>>>(esrc, edst, al_s, al_d, earr, menc);
    edge_exp<<<egrid, ZB, 0, stream>>>(edst, earr, menc, den);
    aggregate<32, false><<<NN, 64, 0, stream>>>(hproj, rowptr, esrc, earr, den,
                                                Bl[3], Gl[3], Bel[3], nullptr, hA);

    // ---- pooling + readout ----
    pool_accum<<<(NN * 32 + ZB - 1) / ZB, ZB, 0, stream>>>(hA, batch, pooled, cnt);
    final_out<<<1, 64, 0, stream>>>(pooled, cnt, Wo, bo, (float*)d_out);
}

// Round 2
// 1398.242 us; speedup vs baseline: 1.3756x; 1.3756x over previous
//
#include <hip/hip_runtime.h>
#include <hip/hip_bf16.h>
#include <cstdint>

// ---- problem constants (HierarchicalBrainGNN) ----
constexpr int NN   = 20000;          // nodes
constexpr int NE   = 320000;         // edges before self loops
constexpr int ETOT = NE + NN;        // with self loops
constexpr int BG   = 8;              // graphs
constexpr int FIN  = 100;
constexpr int HID  = 256;
constexpr int H    = 4;              // heads
constexpr float SLOPE  = 0.2f;
constexpr float LN_EPS = 1e-5f;

#define DEVFN __device__ __forceinline__

typedef __bf16 bf16x8 __attribute__((ext_vector_type(8)));
typedef float  f32x4  __attribute__((ext_vector_type(4)));

DEVFN float lrelu(float v) { return v > 0.f ? v : SLOPE * v; }
DEVFN unsigned encf(float f) {
    unsigned u = __float_as_uint(f);
    return (u & 0x80000000u) ? ~u : (u | 0x80000000u);
}
DEVFN float decf(unsigned u) {
    return (u & 0x80000000u) ? __uint_as_float(u & 0x7fffffffu) : __uint_as_float(~u);
}
// fp32 -> bf16 bits, round-nearest-even (finite inputs)
DEVFN ushort f2bf(float f) {
    unsigned u = __float_as_uint(f);
    return (ushort)((u + 0x7fffu + ((u >> 16) & 1u)) >> 16);
}

// ---------------- utility ----------------
__global__ void zero_u32(uint32_t* __restrict__ p, int n) {
    int i = blockIdx.x * blockDim.x + threadIdx.x;
    if (i < n) p[i] = 0u;
}

// ---------------- CSR build ----------------
__global__ void count_deg(const int* __restrict__ ei, int* __restrict__ deg) {
    int k = blockIdx.x * blockDim.x + threadIdx.x;
    if (k >= ETOT) return;
    int d = (k < NE) ? ei[NE + k] : (k - NE);
    atomicAdd(&deg[d], 1);
}

__global__ void scan_kernel(const int* __restrict__ deg, int* __restrict__ rowptr) {
    __shared__ int buf[1024];
    int carry = 0;
    for (int base = 0; base < NN; base += 1024) {
        int i = base + threadIdx.x;
        int v = (i < NN) ? deg[i] : 0;
        buf[threadIdx.x] = v;
        __syncthreads();
        for (int off = 1; off < 1024; off <<= 1) {
            int t = (threadIdx.x >= off) ? buf[threadIdx.x - off] : 0;
            __syncthreads();
            buf[threadIdx.x] += t;
            __syncthreads();
        }
        int incl = buf[threadIdx.x];
        if (i < NN) rowptr[i] = carry + incl - v;   // exclusive prefix
        int total = buf[1023];
        __syncthreads();
        carry += total;
    }
    if (threadIdx.x == 0) rowptr[NN] = carry;
}

__global__ void scatter_edges(const int* __restrict__ ei, const int* __restrict__ rowptr,
                              int* __restrict__ fill, int* __restrict__ esrc,
                              int* __restrict__ edst) {
    int k = blockIdx.x * blockDim.x + threadIdx.x;
    if (k >= ETOT) return;
    int s, d;
    if (k < NE) { s = ei[k]; d = ei[NE + k]; }
    else        { s = k - NE; d = k - NE; }
    int pos = rowptr[d] + atomicAdd(&fill[d], 1);
    esrc[pos] = s;
    edst[pos] = d;
}

// ---------------- fp32 GEMM (input layer only): C = relu(A@W + b), bf16 shadow ----------------
template <int K, int NC, int TM>
__global__ void gemm_rows(const float* __restrict__ A, const float* __restrict__ W,
                          const float* __restrict__ bias, float* __restrict__ C,
                          ushort* __restrict__ Cbf, int M) {
    __shared__ float As[TM][K];
    int row0 = blockIdx.x * TM;
    for (int idx = threadIdx.x; idx < TM * K; idx += blockDim.x) {
        int r = idx / K, k = idx - r * K;
        int gr = row0 + r;
        As[r][k] = (gr < M) ? A[(size_t)gr * K + k] : 0.f;
    }
    __syncthreads();
    for (int c = threadIdx.x; c < NC; c += blockDim.x) {
        float acc[TM];
#pragma unroll
        for (int r = 0; r < TM; r++) acc[r] = 0.f;
        for (int k = 0; k < K; k++) {
            float w = W[(size_t)k * NC + c];
#pragma unroll
            for (int r = 0; r < TM; r++) acc[r] += As[r][k] * w;
        }
        float bv = bias[c];
#pragma unroll
        for (int r = 0; r < TM; r++) {
            int gr = row0 + r;
            if (gr < M) {
                float v = fmaxf(acc[r] + bv, 0.f);
                C[(size_t)gr * NC + c] = v;
                Cbf[(size_t)gr * NC + c] = f2bf(v);
            }
        }
    }
}

// ---------------- W convert+transpose: Wt[NC][K] bf16 from W[K][NC] fp32 ----------------
template <int K, int NC>
__global__ void convW(const float* __restrict__ W, ushort* __restrict__ Wt) {
    int id = blockIdx.x * blockDim.x + threadIdx.x;
    if (id >= K * NC) return;
    int k = id / NC, n = id - k * NC;
    Wt[(size_t)n * K + k] = f2bf(W[id]);
}

// ---------------- MFMA bf16 GEMM: C[M,NC] fp32 = A[M,K]bf16 @ Wt[NC,K]^T ----------------
// 64x64 tile, 4 waves; wave w owns rows [w*16,w*16+16), 4 col tiles of 16.
// A-frag: A[m=lane&15][k=quad*8+j]; B-frag: B[k=quad*8+j][n=lane&15];
// D: col=lane&15, row=quad*4+reg  (verified layouts, cdna_hip_programming §3)
template <int K, int NC>
__launch_bounds__(256)
__global__ void gemm_mfma(const ushort* __restrict__ A, const ushort* __restrict__ Wt,
                          float* __restrict__ C, int M) {
    constexpr int LDK = K + 8;            // pad keeps 16B align, breaks pow2 stride
    __shared__ ushort As[64 * LDK];
    __shared__ ushort Bs[64 * LDK];
    const int row0 = blockIdx.x * 64;
    const int col0 = blockIdx.y * 64;
    const int tid = threadIdx.x;
    constexpr int CH = K / 8;             // 16B chunks per row
    for (int c = tid; c < 64 * CH; c += 256) {
        int r = c / CH, cc = c - r * CH;
        int gr = row0 + r;
        uint4 v = make_uint4(0u, 0u, 0u, 0u);
        if (gr < M) v = *(const uint4*)(A + (size_t)gr * K + cc * 8);
        *(uint4*)(&As[r * LDK + cc * 8]) = v;
        uint4 w = *(const uint4*)(Wt + (size_t)(col0 + r) * K + cc * 8);
        *(uint4*)(&Bs[r * LDK + cc * 8]) = w;
    }
    __syncthreads();
    const int wave = tid >> 6;
    const int lane = tid & 63;
    const int m = lane & 15;
    const int q = lane >> 4;
    f32x4 acc0 = {0.f, 0.f, 0.f, 0.f}, acc1 = acc0, acc2 = acc0, acc3 = acc0;
    const ushort* ap  = &As[(wave * 16 + m) * LDK + q * 8];
    const ushort* bp0 = &Bs[(0 * 16 + m) * LDK + q * 8];
    const ushort* bp1 = &Bs[(1 * 16 + m) * LDK + q * 8];
    const ushort* bp2 = &Bs[(2 * 16 + m) * LDK + q * 8];
    const ushort* bp3 = &Bs[(3 * 16 + m) * LDK + q * 8];
#pragma unroll
    for (int kk = 0; kk < K / 32; kk++) {
        bf16x8 a = *(const bf16x8*)(ap + kk * 32);
        acc0 = __builtin_amdgcn_mfma_f32_16x16x32_bf16(a, *(const bf16x8*)(bp0 + kk * 32), acc0, 0, 0, 0);
        acc1 = __builtin_amdgcn_mfma_f32_16x16x32_bf16(a, *(const bf16x8*)(bp1 + kk * 32), acc1, 0, 0, 0);
        acc2 = __builtin_amdgcn_mfma_f32_16x16x32_bf16(a, *(const bf16x8*)(bp2 + kk * 32), acc2, 0, 0, 0);
        acc3 = __builtin_amdgcn_mfma_f32_16x16x32_bf16(a, *(const bf16x8*)(bp3 + kk * 32), acc3, 0, 0, 0);
    }
    const int grow0 = row0 + wave * 16 + q * 4;
    float* Cb = C + (size_t)grow0 * NC + col0 + m;
#pragma unroll
    for (int r = 0; r < 4; r++) {
        if (grow0 + r < M) {
            Cb[(size_t)r * NC + 0]  = acc0[r];
            Cb[(size_t)r * NC + 16] = acc1[r];
            Cb[(size_t)r * NC + 32] = acc2[r];
            Cb[(size_t)r * NC + 48] = acc3[r];
        }
    }
}

// ---------------- attention logits: al_s/al_d [N,H] ----------------
template <int DO>
__global__ void compute_al(const float* __restrict__ hproj, const float* __restrict__ a_s,
                           const float* __restrict__ a_d, float* __restrict__ al_s,
                           float* __restrict__ al_d) {
    int n = blockIdx.x;
    int head = threadIdx.x >> 6;   // 4 waves, one head each
    int lane = threadIdx.x & 63;
    const float* hp = hproj + (size_t)n * H * DO + head * DO;
    float ss = 0.f, sd = 0.f;
    for (int c = lane; c < DO; c += 64) {
        float v = hp[c];
        ss += v * a_s[head * DO + c];
        sd += v * a_d[head * DO + c];
    }
#pragma unroll
    for (int off = 32; off > 0; off >>= 1) {
        ss += __shfl_down(ss, off);
        sd += __shfl_down(sd, off);
    }
    if (lane == 0) {
        al_s[n * H + head] = ss;
        al_d[n * H + head] = sd;
    }
}

// ---------------- edge passes ----------------
__global__ void edge_max(const int* __restrict__ esrc, const int* __restrict__ edst,
                         const float* __restrict__ al_s, const float* __restrict__ al_d,
                         float* __restrict__ earr, unsigned* __restrict__ menc) {
    int p = blockIdx.x * blockDim.x + threadIdx.x;
    if (p >= ETOT) return;
    int s = esrc[p], d = edst[p];
    float4 s4 = *(const float4*)(al_s + 4 * (size_t)s);
    float4 d4 = *(const float4*)(al_d + 4 * (size_t)d);
    float e0 = lrelu(s4.x + d4.x);
    float e1 = lrelu(s4.y + d4.y);
    float e2 = lrelu(s4.z + d4.z);
    float e3 = lrelu(s4.w + d4.w);
    ((float4*)earr)[p] = make_float4(e0, e1, e2, e3);
    atomicMax(&menc[4 * d + 0], encf(e0));
    atomicMax(&menc[4 * d + 1], encf(e1));
    atomicMax(&menc[4 * d + 2], encf(e2));
    atomicMax(&menc[4 * d + 3], encf(e3));
}

__global__ void edge_exp(const int* __restrict__ edst, float* __restrict__ earr,
                         const unsigned* __restrict__ menc, float* __restrict__ den) {
    int p = blockIdx.x * blockDim.x + threadIdx.x;
    if (p >= ETOT) return;
    int d = edst[p];
    float4 e = ((const float4*)earr)[p];
    float x0 = expf(e.x - decf(menc[4 * d + 0]));
    float x1 = expf(e.y - decf(menc[4 * d + 1]));
    float x2 = expf(e.z - decf(menc[4 * d + 2]));
    float x3 = expf(e.w - decf(menc[4 * d + 3]));
    ((float4*)earr)[p] = make_float4(x0, x1, x2, x3);
    atomicAdd(&den[4 * d + 0], x0);
    atomicAdd(&den[4 * d + 1], x1);
    atomicAdd(&den[4 * d + 2], x2);
    atomicAdd(&den[4 * d + 3], x3);
}

// ---------------- aggregate + head-mean + bias + relu + LN (+residual) ----------------
template <int DO, bool RESID, bool EMITBF>
__global__ void aggregate(const float* __restrict__ hproj, const int* __restrict__ rowptr,
                          const int* __restrict__ esrc, const float* __restrict__ earr,
                          const float* __restrict__ den, const float* __restrict__ bias,
                          const float* __restrict__ gamma, const float* __restrict__ beta,
                          const float* __restrict__ hprev, float* __restrict__ hout,
                          ushort* __restrict__ houtbf) {
    constexpr int BD = (DO < 64) ? 64 : DO;
    __shared__ float red[BD];
    int n = blockIdx.x;
    int c = threadIdx.x;

    float4 dn = *(const float4*)(den + 4 * (size_t)n);
    float i0 = 1.f / (dn.x + 1e-16f);
    float i1 = 1.f / (dn.y + 1e-16f);
    float i2 = 1.f / (dn.z + 1e-16f);
    float i3 = 1.f / (dn.w + 1e-16f);

    float a0 = 0.f, a1 = 0.f, a2 = 0.f, a3 = 0.f;
    int p0 = rowptr[n], p1 = rowptr[n + 1];
    for (int p = p0; p < p1; p++) {
        int s = esrc[p];
        float4 ex = ((const float4*)earr)[p];
        if (c < DO) {
            const float* hp = hproj + (size_t)s * (H * DO);
            a0 += (ex.x * i0) * hp[c];
            a1 += (ex.y * i1) * hp[DO + c];
            a2 += (ex.z * i2) * hp[2 * DO + c];
            a3 += (ex.w * i3) * hp[3 * DO + c];
        }
    }
    float val = 0.f;
    if (c < DO) {
        val = 0.25f * (a0 + a1 + a2 + a3) + bias[c];
        val = fmaxf(val, 0.f);   // relu before LN
    }
    red[threadIdx.x] = (c < DO) ? val : 0.f;
    __syncthreads();
    for (int off = BD / 2; off > 0; off >>= 1) {
        if (threadIdx.x < off) red[threadIdx.x] += red[threadIdx.x + off];
        __syncthreads();
    }
    float mu = red[0] / DO;
    __syncthreads();
    float dv = (c < DO) ? (val - mu) : 0.f;
    red[threadIdx.x] = dv * dv;
    __syncthreads();
    for (int off = BD / 2; off > 0; off >>= 1) {
        if (threadIdx.x < off) red[threadIdx.x] += red[threadIdx.x + off];
        __syncthreads();
    }
    float var = red[0] / DO;
    if (c < DO) {
        float o = dv * rsqrtf(var + LN_EPS) * gamma[c] + beta[c];
        if (RESID) o += hprev[(size_t)n * DO + c];
        hout[(size_t)n * DO + c] = o;
        if (EMITBF) houtbf[(size_t)n * DO + c] = f2bf(o);
    }
}

// ---------------- pooling (hierarchical) + readout ----------------
__global__ void pool_accum2(const float* __restrict__ h, const int* __restrict__ batch,
                            float* __restrict__ pooled, float* __restrict__ cnt) {
    __shared__ float lp[BG * 32];
    __shared__ float lc[BG];
    for (int i = threadIdx.x; i < BG * 32; i += blockDim.x) lp[i] = 0.f;
    if (threadIdx.x < BG) lc[threadIdx.x] = 0.f;
    __syncthreads();
    int c = threadIdx.x & 31;
    int rb = threadIdx.x >> 5;                 // 8 rows per 256-thread block
    for (int n = blockIdx.x * 8 + rb; n < NN; n += gridDim.x * 8) {
        int b = batch[n];
        atomicAdd(&lp[b * 32 + c], h[(size_t)n * 32 + c]);
        if (c == 0) atomicAdd(&lc[b], 1.f);
    }
    __syncthreads();
    for (int i = threadIdx.x; i < BG * 32; i += blockDim.x) atomicAdd(&pooled[i], lp[i]);
    if (threadIdx.x < BG) atomicAdd(&cnt[threadIdx.x], lc[threadIdx.x]);
}

__global__ void final_out(const float* __restrict__ pooled, const float* __restrict__ cnt,
                          const float* __restrict__ Wo, const float* __restrict__ bo,
                          float* __restrict__ out) {
    int b = threadIdx.x;
    if (b < BG) {
        float inv = 1.f / fmaxf(cnt[b], 1.f);
        float acc = 0.f;
        for (int c = 0; c < 32; c++) acc += pooled[b * 32 + c] * inv * Wo[c];
        out[b] = acc + bo[0];
    }
}

// ---------------- host orchestration ----------------
extern "C" void kernel_launch(void* const* d_in, const int* in_sizes, int n_in,
                              void* d_out, int out_size, void* d_ws, size_t ws_size,
                              hipStream_t stream) {
    const float* x     = (const float*)d_in[0];
    const int*   ei    = (const int*)d_in[1];
    const int*   batch = (const int*)d_in[2];
    const float* Wi    = (const float*)d_in[3];
    const float* bi    = (const float*)d_in[4];
    const float* Wl[4]  = {(const float*)d_in[5],  (const float*)d_in[11], (const float*)d_in[17], (const float*)d_in[23]};
    const float* Asl[4] = {(const float*)d_in[6],  (const float*)d_in[12], (const float*)d_in[18], (const float*)d_in[24]};
    const float* Adl[4] = {(const float*)d_in[7],  (const float*)d_in[13], (const float*)d_in[19], (const float*)d_in[25]};
    const float* Bl[4]  = {(const float*)d_in[8],  (const float*)d_in[14], (const float*)d_in[20], (const float*)d_in[26]};
    const float* Gl[4]  = {(const float*)d_in[9],  (const float*)d_in[15], (const float*)d_in[21], (const float*)d_in[27]};
    const float* Bel[4] = {(const float*)d_in[10], (const float*)d_in[16], (const float*)d_in[22], (const float*)d_in[28]};
    const float* Wo = (const float*)d_in[29];
    const float* bo = (const float*)d_in[30];

    char* p = (char*)d_ws;
    auto take = [&](size_t bytes) -> void* {
        void* r = (void*)p;
        p += (bytes + 255) & ~(size_t)255;
        return r;
    };
    float*    hA     = (float*)take((size_t)NN * HID * 4);
    float*    hB     = (float*)take((size_t)NN * HID * 4);
    ushort*   hAbf   = (ushort*)take((size_t)NN * HID * 2);
    ushort*   hBbf   = (ushort*)take((size_t)NN * HID * 2);
    float*    hproj  = (float*)take((size_t)NN * H * HID * 4);
    float*    al_s   = (float*)take((size_t)NN * H * 4);
    float*    al_d   = (float*)take((size_t)NN * H * 4);
    unsigned* menc   = (unsigned*)take((size_t)NN * H * 4);  // adjacent to den
    float*    den    = (float*)take((size_t)NN * H * 4);
    float*    earr   = (float*)take((size_t)ETOT * H * 4);
    int*      deg    = (int*)take((size_t)NN * 4);
    int*      fill   = (int*)take((size_t)NN * 4);
    int*      rowptr = (int*)take((size_t)(NN + 1) * 4);
    int*      esrc   = (int*)take((size_t)ETOT * 4);
    int*      edst   = (int*)take((size_t)ETOT * 4);
    float*    pooled = (float*)take((size_t)BG * 32 * 4);   // adjacent to cnt
    float*    cnt    = (float*)take((size_t)BG * 4);
    ushort*   wt0    = (ushort*)take((size_t)1024 * 256 * 2);
    ushort*   wt1    = (ushort*)take((size_t)512 * 256 * 2);
    ushort*   wt2    = (ushort*)take((size_t)256 * 128 * 2);
    ushort*   wt3    = (ushort*)take((size_t)128 * 64 * 2);
    (void)ws_size; (void)n_in; (void)in_sizes; (void)out_size; (void)cnt;

    const int ZB = 256;
    const int egrid = (ETOT + ZB - 1) / ZB;
    const int ggrid = (NN + 7) / 8;
    const int mtiles = (NN + 63) / 64;       // 313

    // zero: deg, fill, pooled+cnt
    zero_u32<<<(NN + ZB - 1) / ZB, ZB, 0, stream>>>((uint32_t*)deg, NN);
    zero_u32<<<(NN + ZB - 1) / ZB, ZB, 0, stream>>>((uint32_t*)fill, NN);
    zero_u32<<<1, ZB, 0, stream>>>((uint32_t*)pooled, BG * 32 + BG + 56);

    // weight conversion (bf16, transposed)
    convW<256, 1024><<<(256 * 1024 + 255) / 256, 256, 0, stream>>>(Wl[0], wt0);
    convW<256, 512><<<(256 * 512 + 255) / 256, 256, 0, stream>>>(Wl[1], wt1);
    convW<128, 256><<<(128 * 256 + 255) / 256, 256, 0, stream>>>(Wl[2], wt2);
    convW<64, 128><<<(64 * 128 + 255) / 256, 256, 0, stream>>>(Wl[3], wt3);

    // CSR by dst
    count_deg<<<egrid, ZB, 0, stream>>>(ei, deg);
    scan_kernel<<<1, 1024, 0, stream>>>(deg, rowptr);
    scatter_edges<<<egrid, ZB, 0, stream>>>(ei, rowptr, fill, esrc, edst);

    // input layer: hA = relu(x @ Wi + bi)  (+ bf16 shadow)
    gemm_rows<FIN, HID, 8><<<ggrid, 256, 0, stream>>>(x, Wi, bi, hA, hAbf, NN);

    // ---- level 0: 256 -> 256, residual ----
    gemm_mfma<256, 1024><<<dim3(mtiles, 16), 256, 0, stream>>>(hAbf, wt0, hproj, NN);
    compute_al<256><<<NN, 256, 0, stream>>>(hproj, Asl[0], Adl[0], al_s, al_d);
    zero_u32<<<(2 * NN * H + ZB - 1) / ZB, ZB, 0, stream>>>((uint32_t*)menc, 2 * NN * H);
    edge_max<<<egrid, ZB, 0, stream>>>(esrc, edst, al_s, al_d, earr, menc);
    edge_exp<<<egrid, ZB, 0, stream>>>(edst, earr, menc, den);
    aggregate<256, true, true><<<NN, 256, 0, stream>>>(hproj, rowptr, esrc, earr, den,
                                                       Bl[0], Gl[0], Bel[0], hA, hB, hBbf);
    // ---- level 1: 256 -> 128 ----
    gemm_mfma<256, 512><<<dim3(mtiles, 8), 256, 0, stream>>>(hBbf, wt1, hproj, NN);
    compute_al<128><<<NN, 256, 0, stream>>>(hproj, Asl[1], Adl[1], al_s, al_d);
    zero_u32<<<(2 * NN * H + ZB - 1) / ZB, ZB, 0, stream>>>((uint32_t*)menc, 2 * NN * H);
    edge_max<<<egrid, ZB, 0, stream>>>(esrc, edst, al_s, al_d, earr, menc);
    edge_exp<<<egrid, ZB, 0, stream>>>(edst, earr, menc, den);
    aggregate<128, false, true><<<NN, 128, 0, stream>>>(hproj, rowptr, esrc, earr, den,
                                                        Bl[1], Gl[1], Bel[1], nullptr, hA, hAbf);
    // ---- level 2: 128 -> 64 ----
    gemm_mfma<128, 256><<<dim3(mtiles, 4), 256, 0, stream>>>(hAbf, wt2, hproj, NN);
    compute_al<64><<<NN, 256, 0, stream>>>(hproj, Asl[2], Adl[2], al_s, al_d);
    zero_u32<<<(2 * NN * H + ZB - 1) / ZB, ZB, 0, stream>>>((uint32_t*)menc, 2 * NN * H);
    edge_max<<<egrid, ZB, 0, stream>>>(esrc, edst, al_s, al_d, earr, menc);
    edge_exp<<<egrid, ZB, 0, stream>>>(edst, earr, menc, den);
    aggregate<64, false, true><<<NN, 64, 0, stream>>>(hproj, rowptr, esrc, earr, den,
                                                      Bl[2], Gl[2], Bel[2], nullptr, hB, hBbf);
    // ---- level 3: 64 -> 32 ----
    gemm_mfma<64, 128><<<dim3(mtiles, 2), 256, 0, stream>>>(hBbf, wt3, hproj, NN);
    compute_al<32><<<NN, 256, 0, stream>>>(hproj, Asl[3], Adl[3], al_s, al_d);
    zero_u32<<<(2 * NN * H + ZB - 1) / ZB, ZB, 0, stream>>>((uint32_t*)menc, 2 * NN * H);
    edge_max<<<egrid, ZB, 0, stream>>>(esrc, edst, al_s, al_d, earr, menc);
    edge_exp<<<egrid, ZB, 0, stream>>>(edst, earr, menc, den);
    aggregate<32, false, false><<<NN, 64, 0, stream>>>(hproj, rowptr, esrc, earr, den,
                                                       Bl[3], Gl[3], Bel[3], nullptr, hA, nullptr);

    // ---- pooling + readout ----
    pool_accum2<<<80, 256, 0, stream>>>(hA, batch, pooled, cnt);
    final_out<<<1, 64, 0, stream>>>(pooled, cnt, Wo, bo, (float*)d_out);
}

// Round 3
// 706.224 us; speedup vs baseline: 2.7236x; 1.9799x over previous
//
#include <hip/hip_runtime.h>
#include <hip/hip_bf16.h>
#include <cstdint>

// ---- problem constants (HierarchicalBrainGNN) ----
constexpr int NN   = 20000;          // nodes
constexpr int NE   = 320000;         // edges before self loops
constexpr int ETOT = NE + NN;        // with self loops
constexpr int BG   = 8;              // graphs
constexpr int FIN  = 100;
constexpr int HID  = 256;
constexpr int H    = 4;              // heads
constexpr float SLOPE  = 0.2f;
constexpr float LN_EPS = 1e-5f;

#define DEVFN __device__ __forceinline__

typedef __bf16 bf16x8 __attribute__((ext_vector_type(8)));
typedef float  f32x4  __attribute__((ext_vector_type(4)));

DEVFN float lrelu(float v) { return v > 0.f ? v : SLOPE * v; }
// fp32 -> bf16 bits, round-nearest-even (finite inputs)
DEVFN ushort f2bf(float f) {
    unsigned u = __float_as_uint(f);
    return (ushort)((u + 0x7fffu + ((u >> 16) & 1u)) >> 16);
}
DEVFN float bf2f(unsigned u) { return __uint_as_float(u << 16); }

// ---------------- utility ----------------
__global__ void zero_u32(uint32_t* __restrict__ p, int n) {
    int i = blockIdx.x * blockDim.x + threadIdx.x;
    if (i < n) p[i] = 0u;
}

// ---------------- CSR build ----------------
__global__ void count_deg(const int* __restrict__ ei, int* __restrict__ deg) {
    int k = blockIdx.x * blockDim.x + threadIdx.x;
    if (k >= ETOT) return;
    int d = (k < NE) ? ei[NE + k] : (k - NE);
    atomicAdd(&deg[d], 1);
}

__global__ void scan_kernel(const int* __restrict__ deg, int* __restrict__ rowptr) {
    __shared__ int buf[1024];
    int carry = 0;
    for (int base = 0; base < NN; base += 1024) {
        int i = base + threadIdx.x;
        int v = (i < NN) ? deg[i] : 0;
        buf[threadIdx.x] = v;
        __syncthreads();
        for (int off = 1; off < 1024; off <<= 1) {
            int t = (threadIdx.x >= off) ? buf[threadIdx.x - off] : 0;
            __syncthreads();
            buf[threadIdx.x] += t;
            __syncthreads();
        }
        int incl = buf[threadIdx.x];
        if (i < NN) rowptr[i] = carry + incl - v;   // exclusive prefix
        int total = buf[1023];
        __syncthreads();
        carry += total;
    }
    if (threadIdx.x == 0) rowptr[NN] = carry;
}

__global__ void scatter_edges(const int* __restrict__ ei, const int* __restrict__ rowptr,
                              int* __restrict__ fill, int* __restrict__ esrc) {
    int k = blockIdx.x * blockDim.x + threadIdx.x;
    if (k >= ETOT) return;
    int s, d;
    if (k < NE) { s = ei[k]; d = ei[NE + k]; }
    else        { s = k - NE; d = k - NE; }
    int pos = rowptr[d] + atomicAdd(&fill[d], 1);
    esrc[pos] = s;
}

// ---------------- weight convert+transpose: Wt[NC][KP] bf16 from W[KS][NC] fp32 ----------------
template <int KS, int KP, int NC>
__global__ void convW(const float* __restrict__ W, ushort* __restrict__ Wt) {
    int id = blockIdx.x * blockDim.x + threadIdx.x;
    if (id >= NC * KP) return;
    int n = id / KP, k = id - n * KP;
    Wt[id] = (k < KS) ? f2bf(W[(size_t)k * NC + n]) : (ushort)0;
}

// ---------------- x convert: xpad[NN][128] bf16 (zero-padded K) ----------------
__global__ void convX(const float* __restrict__ x, ushort* __restrict__ xpad) {
    int id = blockIdx.x * blockDim.x + threadIdx.x;
    if (id >= NN * 128) return;
    int n = id >> 7, k = id & 127;
    xpad[id] = (k < FIN) ? f2bf(x[(size_t)n * FIN + k]) : (ushort)0;
}

// ---------------- MFMA bf16 GEMM: Cbf[M,NC] bf16 = A[M,K]bf16 @ Wt[NC,K]^T (+bias,relu) ------
// 64x64 tile, 4 waves; wave w owns rows [w*16,w*16+16), 4 col tiles of 16.
// A-frag: A[m=lane&15][k=quad*8+j]; B-frag: B[k=quad*8+j][n=lane&15];
// D: col=lane&15, row=quad*4+reg  (verified round 2)
template <int K, int NC, bool BR>
__launch_bounds__(256)
__global__ void gemm_mfma(const ushort* __restrict__ A, const ushort* __restrict__ Wt,
                          const float* __restrict__ bias, ushort* __restrict__ Cbf, int M) {
    constexpr int LDK = K + 8;
    __shared__ ushort As[64 * LDK];
    __shared__ ushort Bs[64 * LDK];
    const int row0 = blockIdx.x * 64;
    const int col0 = blockIdx.y * 64;
    const int tid = threadIdx.x;
    constexpr int CH = K / 8;
    for (int c = tid; c < 64 * CH; c += 256) {
        int r = c / CH, cc = c - r * CH;
        int gr = row0 + r;
        uint4 v = make_uint4(0u, 0u, 0u, 0u);
        if (gr < M) v = *(const uint4*)(A + (size_t)gr * K + cc * 8);
        *(uint4*)(&As[r * LDK + cc * 8]) = v;
        uint4 w = *(const uint4*)(Wt + (size_t)(col0 + r) * K + cc * 8);
        *(uint4*)(&Bs[r * LDK + cc * 8]) = w;
    }
    __syncthreads();
    const int wave = tid >> 6;
    const int lane = tid & 63;
    const int m = lane & 15;
    const int q = lane >> 4;
    f32x4 acc0 = {0.f, 0.f, 0.f, 0.f}, acc1 = acc0, acc2 = acc0, acc3 = acc0;
    const ushort* ap  = &As[(wave * 16 + m) * LDK + q * 8];
    const ushort* bp0 = &Bs[(0 * 16 + m) * LDK + q * 8];
    const ushort* bp1 = &Bs[(1 * 16 + m) * LDK + q * 8];
    const ushort* bp2 = &Bs[(2 * 16 + m) * LDK + q * 8];
    const ushort* bp3 = &Bs[(3 * 16 + m) * LDK + q * 8];
#pragma unroll
    for (int kk = 0; kk < K / 32; kk++) {
        bf16x8 a = *(const bf16x8*)(ap + kk * 32);
        acc0 = __builtin_amdgcn_mfma_f32_16x16x32_bf16(a, *(const bf16x8*)(bp0 + kk * 32), acc0, 0, 0, 0);
        acc1 = __builtin_amdgcn_mfma_f32_16x16x32_bf16(a, *(const bf16x8*)(bp1 + kk * 32), acc1, 0, 0, 0);
        acc2 = __builtin_amdgcn_mfma_f32_16x16x32_bf16(a, *(const bf16x8*)(bp2 + kk * 32), acc2, 0, 0, 0);
        acc3 = __builtin_amdgcn_mfma_f32_16x16x32_bf16(a, *(const bf16x8*)(bp3 + kk * 32), acc3, 0, 0, 0);
    }
    const int grow0 = row0 + wave * 16 + q * 4;
    ushort* Cb = Cbf + (size_t)grow0 * NC + col0 + m;
    float b0 = 0, b1 = 0, b2 = 0, b3 = 0;
    if (BR) {
        b0 = bias[col0 + m];      b1 = bias[col0 + m + 16];
        b2 = bias[col0 + m + 32]; b3 = bias[col0 + m + 48];
    }
#pragma unroll
    for (int r = 0; r < 4; r++) {
        if (grow0 + r < M) {
            float v0 = acc0[r], v1 = acc1[r], v2 = acc2[r], v3 = acc3[r];
            if (BR) {
                v0 = fmaxf(v0 + b0, 0.f); v1 = fmaxf(v1 + b1, 0.f);
                v2 = fmaxf(v2 + b2, 0.f); v3 = fmaxf(v3 + b3, 0.f);
            }
            Cb[(size_t)r * NC + 0]  = f2bf(v0);
            Cb[(size_t)r * NC + 16] = f2bf(v1);
            Cb[(size_t)r * NC + 32] = f2bf(v2);
            Cb[(size_t)r * NC + 48] = f2bf(v3);
        }
    }
}

// ---------------- attention logits: al_s/al_d [N,H] ----------------
template <int DO>
__global__ void compute_al(const ushort* __restrict__ hproj, const float* __restrict__ a_s,
                           const float* __restrict__ a_d, float* __restrict__ al_s,
                           float* __restrict__ al_d) {
    int n = blockIdx.x;
    int head = threadIdx.x >> 6;   // 4 waves, one head each
    int lane = threadIdx.x & 63;
    const unsigned* hp = (const unsigned*)(hproj + (size_t)n * H * DO + head * DO);
    float ss = 0.f, sd = 0.f;
    for (int cp = lane; cp < DO / 2; cp += 64) {
        unsigned v = hp[cp];
        float lo = bf2f(v & 0xffffu), hi = bf2f(v >> 16);
        ss += lo * a_s[head * DO + 2 * cp] + hi * a_s[head * DO + 2 * cp + 1];
        sd += lo * a_d[head * DO + 2 * cp] + hi * a_d[head * DO + 2 * cp + 1];
    }
#pragma unroll
    for (int off = 32; off > 0; off >>= 1) {
        ss += __shfl_down(ss, off);
        sd += __shfl_down(sd, off);
    }
    if (lane == 0) {
        al_s[n * H + head] = ss;
        al_d[n * H + head] = sd;
    }
}

// ---------------- fused segment softmax: one wave per dst, writes normalized alpha ----------
__global__ void softmax_csr(const int* __restrict__ rowptr, const int* __restrict__ esrc,
                            const float* __restrict__ al_s, const float* __restrict__ al_d,
                            float4* __restrict__ alpha) {
    int wid = (blockIdx.x * blockDim.x + threadIdx.x) >> 6;
    int lane = threadIdx.x & 63;
    if (wid >= NN) return;
    int p0 = rowptr[wid], p1 = rowptr[wid + 1];
    float4 d4 = ((const float4*)al_d)[wid];
    float m0 = -1e30f, m1 = -1e30f, m2 = -1e30f, m3 = -1e30f;
    for (int p = p0 + lane; p < p1; p += 64) {
        int s = esrc[p];
        float4 s4 = ((const float4*)al_s)[s];
        m0 = fmaxf(m0, lrelu(s4.x + d4.x));
        m1 = fmaxf(m1, lrelu(s4.y + d4.y));
        m2 = fmaxf(m2, lrelu(s4.z + d4.z));
        m3 = fmaxf(m3, lrelu(s4.w + d4.w));
    }
#pragma unroll
    for (int off = 32; off > 0; off >>= 1) {
        m0 = fmaxf(m0, __shfl_xor(m0, off));
        m1 = fmaxf(m1, __shfl_xor(m1, off));
        m2 = fmaxf(m2, __shfl_xor(m2, off));
        m3 = fmaxf(m3, __shfl_xor(m3, off));
    }
    float s0 = 0.f, s1 = 0.f, s2 = 0.f, s3 = 0.f;
    for (int p = p0 + lane; p < p1; p += 64) {
        int s = esrc[p];
        float4 s4 = ((const float4*)al_s)[s];
        s0 += __expf(lrelu(s4.x + d4.x) - m0);
        s1 += __expf(lrelu(s4.y + d4.y) - m1);
        s2 += __expf(lrelu(s4.z + d4.z) - m2);
        s3 += __expf(lrelu(s4.w + d4.w) - m3);
    }
#pragma unroll
    for (int off = 32; off > 0; off >>= 1) {
        s0 += __shfl_xor(s0, off);
        s1 += __shfl_xor(s1, off);
        s2 += __shfl_xor(s2, off);
        s3 += __shfl_xor(s3, off);
    }
    float i0 = 1.f / (s0 + 1e-16f), i1 = 1.f / (s1 + 1e-16f);
    float i2 = 1.f / (s2 + 1e-16f), i3 = 1.f / (s3 + 1e-16f);
    for (int p = p0 + lane; p < p1; p += 64) {
        int s = esrc[p];
        float4 s4 = ((const float4*)al_s)[s];
        alpha[p] = make_float4(__expf(lrelu(s4.x + d4.x) - m0) * i0,
                               __expf(lrelu(s4.y + d4.y) - m1) * i1,
                               __expf(lrelu(s4.z + d4.z) - m2) * i2,
                               __expf(lrelu(s4.w + d4.w) - m3) * i3);
    }
}

// ------- aggregate (bf16 gather) + head-mean + bias + relu + LN (+residual), bf16 out -------
template <int DO, bool RESID>
__global__ void aggregate(const ushort* __restrict__ hproj, const int* __restrict__ rowptr,
                          const int* __restrict__ esrc, const float4* __restrict__ alpha,
                          const float* __restrict__ bias, const float* __restrict__ gamma,
                          const float* __restrict__ beta, const ushort* __restrict__ hprev,
                          ushort* __restrict__ hout) {
    constexpr int HDO2 = H * DO / 2;                 // uint (bf16x2) slots per row
    constexpr int BD   = (HDO2 > 256) ? 256 : HDO2;  // block size
    constexpr int PER  = HDO2 / BD;                  // slots per thread
    constexpr int DO2  = DO / 2;
    __shared__ float2 part[HDO2];
    __shared__ float red[BD];
    int n = blockIdx.x;
    int tid = threadIdx.x;
    int p0 = rowptr[n], p1 = rowptr[n + 1];
    float2 acc[PER];
#pragma unroll
    for (int j = 0; j < PER; j++) acc[j] = make_float2(0.f, 0.f);
    for (int p = p0; p < p1; p++) {
        int s = esrc[p];
        float4 al = alpha[p];
        const unsigned* hp = (const unsigned*)(hproj + (size_t)s * (H * DO));
#pragma unroll
        for (int j = 0; j < PER; j++) {
            int idx = j * BD + tid;
            unsigned v = hp[idx];
            int head = idx / DO2;
            float a = (head == 0) ? al.x : (head == 1) ? al.y : (head == 2) ? al.z : al.w;
            acc[j].x += a * bf2f(v & 0xffffu);
            acc[j].y += a * bf2f(v >> 16);
        }
    }
#pragma unroll
    for (int j = 0; j < PER; j++) part[j * BD + tid] = acc[j];
    __syncthreads();
    float v0 = 0.f, v1 = 0.f;
    if (tid < DO2) {
#pragma unroll
        for (int h = 0; h < H; h++) {
            float2 t = part[h * DO2 + tid];
            v0 += t.x; v1 += t.y;
        }
        v0 = fmaxf(0.25f * v0 + bias[2 * tid], 0.f);
        v1 = fmaxf(0.25f * v1 + bias[2 * tid + 1], 0.f);
    }
    red[tid] = (tid < DO2) ? (v0 + v1) : 0.f;
    __syncthreads();
    for (int off = BD / 2; off > 0; off >>= 1) {
        if (tid < off) red[tid] += red[tid + off];
        __syncthreads();
    }
    float mu = red[0] / DO;
    __syncthreads();
    float d0 = v0 - mu, d1 = v1 - mu;
    red[tid] = (tid < DO2) ? (d0 * d0 + d1 * d1) : 0.f;
    __syncthreads();
    for (int off = BD / 2; off > 0; off >>= 1) {
        if (tid < off) red[tid] += red[tid + off];
        __syncthreads();
    }
    float rstd = rsqrtf(red[0] / DO + LN_EPS);
    if (tid < DO2) {
        float o0 = d0 * rstd * gamma[2 * tid]     + beta[2 * tid];
        float o1 = d1 * rstd * gamma[2 * tid + 1] + beta[2 * tid + 1];
        if (RESID) {
            unsigned pv = ((const unsigned*)(hprev + (size_t)n * DO))[tid];
            o0 += bf2f(pv & 0xffffu);
            o1 += bf2f(pv >> 16);
        }
        unsigned ob = (unsigned)f2bf(o0) | ((unsigned)f2bf(o1) << 16);
        ((unsigned*)(hout + (size_t)n * DO))[tid] = ob;
    }
}

// ---------------- pooling (hierarchical) + readout ----------------
__global__ void pool_accum2(const ushort* __restrict__ h, const int* __restrict__ batch,
                            float* __restrict__ pooled, float* __restrict__ cnt) {
    __shared__ float lp[BG * 32];
    __shared__ float lc[BG];
    for (int i = threadIdx.x; i < BG * 32; i += blockDim.x) lp[i] = 0.f;
    if (threadIdx.x < BG) lc[threadIdx.x] = 0.f;
    __syncthreads();
    int c = threadIdx.x & 31;
    int rb = threadIdx.x >> 5;
    for (int n = blockIdx.x * 8 + rb; n < NN; n += gridDim.x * 8) {
        int b = batch[n];
        atomicAdd(&lp[b * 32 + c], bf2f((unsigned)h[(size_t)n * 32 + c]));
        if (c == 0) atomicAdd(&lc[b], 1.f);
    }
    __syncthreads();
    for (int i = threadIdx.x; i < BG * 32; i += blockDim.x) atomicAdd(&pooled[i], lp[i]);
    if (threadIdx.x < BG) atomicAdd(&cnt[threadIdx.x], lc[threadIdx.x]);
}

__global__ void final_out(const float* __restrict__ pooled, const float* __restrict__ cnt,
                          const float* __restrict__ Wo, const float* __restrict__ bo,
                          float* __restrict__ out) {
    int b = threadIdx.x;
    if (b < BG) {
        float inv = 1.f / fmaxf(cnt[b], 1.f);
        float acc = 0.f;
        for (int c = 0; c < 32; c++) acc += pooled[b * 32 + c] * inv * Wo[c];
        out[b] = acc + bo[0];
    }
}

// ---------------- host orchestration ----------------
extern "C" void kernel_launch(void* const* d_in, const int* in_sizes, int n_in,
                              void* d_out, int out_size, void* d_ws, size_t ws_size,
                              hipStream_t stream) {
    const float* x     = (const float*)d_in[0];
    const int*   ei    = (const int*)d_in[1];
    const int*   batch = (const int*)d_in[2];
    const float* Wi    = (const float*)d_in[3];
    const float* bi    = (const float*)d_in[4];
    const float* Wl[4]  = {(const float*)d_in[5],  (const float*)d_in[11], (const float*)d_in[17], (const float*)d_in[23]};
    const float* Asl[4] = {(const float*)d_in[6],  (const float*)d_in[12], (const float*)d_in[18], (const float*)d_in[24]};
    const float* Adl[4] = {(const float*)d_in[7],  (const float*)d_in[13], (const float*)d_in[19], (const float*)d_in[25]};
    const float* Bl[4]  = {(const float*)d_in[8],  (const float*)d_in[14], (const float*)d_in[20], (const float*)d_in[26]};
    const float* Gl[4]  = {(const float*)d_in[9],  (const float*)d_in[15], (const float*)d_in[21], (const float*)d_in[27]};
    const float* Bel[4] = {(const float*)d_in[10], (const float*)d_in[16], (const float*)d_in[22], (const float*)d_in[28]};
    const float* Wo = (const float*)d_in[29];
    const float* bo = (const float*)d_in[30];

    char* p = (char*)d_ws;
    auto take = [&](size_t bytes) -> void* {
        void* r = (void*)p;
        p += (bytes + 255) & ~(size_t)255;
        return r;
    };
    ushort*   hAbf   = (ushort*)take((size_t)NN * HID * 2);
    ushort*   hBbf   = (ushort*)take((size_t)NN * HID * 2);
    ushort*   hproj  = (ushort*)take((size_t)NN * H * HID * 2);
    ushort*   xpad   = (ushort*)take((size_t)NN * 128 * 2);
    float*    al_s   = (float*)take((size_t)NN * H * 4);
    float*    al_d   = (float*)take((size_t)NN * H * 4);
    float4*   alpha  = (float4*)take((size_t)ETOT * 16);
    int*      deg    = (int*)take((size_t)NN * 4);
    int*      fill   = (int*)take((size_t)NN * 4);
    int*      rowptr = (int*)take((size_t)(NN + 1) * 4);
    int*      esrc   = (int*)take((size_t)ETOT * 4);
    float*    pooled = (float*)take((size_t)BG * 32 * 4);   // adjacent to cnt
    float*    cnt    = (float*)take((size_t)BG * 4);
    ushort*   wti    = (ushort*)take((size_t)256 * 128 * 2);
    ushort*   wt0    = (ushort*)take((size_t)1024 * 256 * 2);
    ushort*   wt1    = (ushort*)take((size_t)512 * 256 * 2);
    ushort*   wt2    = (ushort*)take((size_t)256 * 128 * 2);
    ushort*   wt3    = (ushort*)take((size_t)128 * 64 * 2);
    (void)ws_size; (void)n_in; (void)in_sizes; (void)out_size;

    const int ZB = 256;
    const int egrid = (ETOT + ZB - 1) / ZB;
    const int mtiles = (NN + 63) / 64;       // 313

    // zero: deg, fill, pooled+cnt (264 u32 -> 2 blocks)
    zero_u32<<<(NN + ZB - 1) / ZB, ZB, 0, stream>>>((uint32_t*)deg, NN);
    zero_u32<<<(NN + ZB - 1) / ZB, ZB, 0, stream>>>((uint32_t*)fill, NN);
    zero_u32<<<2, ZB, 0, stream>>>((uint32_t*)pooled, BG * 32 + BG);

    // weight conversion (bf16, transposed; input weight K-padded 100->128)
    convW<FIN, 128, 256><<<(256 * 128 + 255) / 256, 256, 0, stream>>>(Wi, wti);
    convW<256, 256, 1024><<<(1024 * 256 + 255) / 256, 256, 0, stream>>>(Wl[0], wt0);
    convW<256, 256, 512><<<(512 * 256 + 255) / 256, 256, 0, stream>>>(Wl[1], wt1);
    convW<128, 128, 256><<<(256 * 128 + 255) / 256, 256, 0, stream>>>(Wl[2], wt2);
    convW<64, 64, 128><<<(128 * 64 + 255) / 256, 256, 0, stream>>>(Wl[3], wt3);
    convX<<<(NN * 128 + 255) / 256, 256, 0, stream>>>(x, xpad);

    // CSR by dst
    count_deg<<<egrid, ZB, 0, stream>>>(ei, deg);
    scan_kernel<<<1, 1024, 0, stream>>>(deg, rowptr);
    scatter_edges<<<egrid, ZB, 0, stream>>>(ei, rowptr, fill, esrc);

    const int sgrid = (NN * 64 + 255) / 256;  // softmax: 1 wave per dst

    // input layer: hAbf = relu(x @ Wi + bi)
    gemm_mfma<128, 256, true><<<dim3(mtiles, 4), 256, 0, stream>>>(xpad, wti, bi, hAbf, NN);

    // ---- level 0: 256 -> 256, residual ----
    gemm_mfma<256, 1024, false><<<dim3(mtiles, 16), 256, 0, stream>>>(hAbf, wt0, nullptr, hproj, NN);
    compute_al<256><<<NN, 256, 0, stream>>>(hproj, Asl[0], Adl[0], al_s, al_d);
    softmax_csr<<<sgrid, 256, 0, stream>>>(rowptr, esrc, al_s, al_d, alpha);
    aggregate<256, true><<<NN, 256, 0, stream>>>(hproj, rowptr, esrc, alpha,
                                                 Bl[0], Gl[0], Bel[0], hAbf, hBbf);
    // ---- level 1: 256 -> 128 ----
    gemm_mfma<256, 512, false><<<dim3(mtiles, 8), 256, 0, stream>>>(hBbf, wt1, nullptr, hproj, NN);
    compute_al<128><<<NN, 256, 0, stream>>>(hproj, Asl[1], Adl[1], al_s, al_d);
    softmax_csr<<<sgrid, 256, 0, stream>>>(rowptr, esrc, al_s, al_d, alpha);
    aggregate<128, false><<<NN, 256, 0, stream>>>(hproj, rowptr, esrc, alpha,
                                                  Bl[1], Gl[1], Bel[1], nullptr, hAbf);
    // ---- level 2: 128 -> 64 ----
    gemm_mfma<128, 256, false><<<dim3(mtiles, 4), 256, 0, stream>>>(hAbf, wt2, nullptr, hproj, NN);
    compute_al<64><<<NN, 256, 0, stream>>>(hproj, Asl[2], Adl[2], al_s, al_d);
    softmax_csr<<<sgrid, 256, 0, stream>>>(rowptr, esrc, al_s, al_d, alpha);
    aggregate<64, false><<<NN, 128, 0, stream>>>(hproj, rowptr, esrc, alpha,
                                                 Bl[2], Gl[2], Bel[2], nullptr, hBbf);
    // ---- level 3: 64 -> 32 ----
    gemm_mfma<64, 128, false><<<dim3(mtiles, 2), 256, 0, stream>>>(hBbf, wt3, nullptr, hproj, NN);
    compute_al<32><<<NN, 256, 0, stream>>>(hproj, Asl[3], Adl[3], al_s, al_d);
    softmax_csr<<<sgrid, 256, 0, stream>>>(rowptr, esrc, al_s, al_d, alpha);
    aggregate<32, false><<<NN, 64, 0, stream>>>(hproj, rowptr, esrc, alpha,
                                                Bl[3], Gl[3], Bel[3], nullptr, hAbf);

    // ---- pooling + readout ----
    pool_accum2<<<80, 256, 0, stream>>>(hAbf, batch, pooled, cnt);
    final_out<<<1, 64, 0, stream>>>(pooled, cnt, Wo, bo, (float*)d_out);
}

// Round 4
// 672.881 us; speedup vs baseline: 2.8586x; 1.0496x over previous
//
#include <hip/hip_runtime.h>
#include <hip/hip_bf16.h>
#include <cstdint>

// ---- problem constants (HierarchicalBrainGNN) ----
constexpr int NN   = 20000;          // nodes
constexpr int NE   = 320000;         // edges before self loops
constexpr int ETOT = NE + NN;        // with self loops
constexpr int BG   = 8;              // graphs
constexpr int FIN  = 100;
constexpr int HID  = 256;
constexpr int H    = 4;              // heads
constexpr float SLOPE  = 0.2f;
constexpr float LN_EPS = 1e-5f;

#define DEVFN __device__ __forceinline__

typedef __bf16 bf16x8 __attribute__((ext_vector_type(8)));
typedef float  f32x4  __attribute__((ext_vector_type(4)));

DEVFN float lrelu(float v) { return v > 0.f ? v : SLOPE * v; }
// fp32 -> bf16 bits, round-nearest-even (finite inputs)
DEVFN ushort f2bf(float f) {
    unsigned u = __float_as_uint(f);
    return (ushort)((u + 0x7fffu + ((u >> 16) & 1u)) >> 16);
}
DEVFN float bf_lo(unsigned u) { return __uint_as_float(u << 16); }
DEVFN float bf_hi(unsigned u) { return __uint_as_float(u & 0xffff0000u); }
DEVFN float bf2f(unsigned u) { return __uint_as_float(u << 16); }

// ---------------- utility ----------------
__global__ void zero_u32(uint32_t* __restrict__ p, int n) {
    int i = blockIdx.x * blockDim.x + threadIdx.x;
    if (i < n) p[i] = 0u;
}

// ---------------- CSR build ----------------
__global__ void count_deg(const int* __restrict__ ei, int* __restrict__ deg) {
    int k = blockIdx.x * blockDim.x + threadIdx.x;
    if (k >= ETOT) return;
    int d = (k < NE) ? ei[NE + k] : (k - NE);
    atomicAdd(&deg[d], 1);
}

__global__ void scan_kernel(const int* __restrict__ deg, int* __restrict__ rowptr) {
    __shared__ int buf[1024];
    int carry = 0;
    for (int base = 0; base < NN; base += 1024) {
        int i = base + threadIdx.x;
        int v = (i < NN) ? deg[i] : 0;
        buf[threadIdx.x] = v;
        __syncthreads();
        for (int off = 1; off < 1024; off <<= 1) {
            int t = (threadIdx.x >= off) ? buf[threadIdx.x - off] : 0;
            __syncthreads();
            buf[threadIdx.x] += t;
            __syncthreads();
        }
        int incl = buf[threadIdx.x];
        if (i < NN) rowptr[i] = carry + incl - v;   // exclusive prefix
        int total = buf[1023];
        __syncthreads();
        carry += total;
    }
    if (threadIdx.x == 0) rowptr[NN] = carry;
}

__global__ void scatter_edges(const int* __restrict__ ei, const int* __restrict__ rowptr,
                              int* __restrict__ fill, int* __restrict__ esrc) {
    int k = blockIdx.x * blockDim.x + threadIdx.x;
    if (k >= ETOT) return;
    int s, d;
    if (k < NE) { s = ei[k]; d = ei[NE + k]; }
    else        { s = k - NE; d = k - NE; }
    int pos = rowptr[d] + atomicAdd(&fill[d], 1);
    esrc[pos] = s;
}

// ---------------- weight convert+transpose: Wt[NC][KP] bf16 from W[KS][NC] fp32 ----------------
template <int KS, int KP, int NC>
__global__ void convW(const float* __restrict__ W, ushort* __restrict__ Wt) {
    int id = blockIdx.x * blockDim.x + threadIdx.x;
    if (id >= NC * KP) return;
    int n = id / KP, k = id - n * KP;
    Wt[id] = (k < KS) ? f2bf(W[(size_t)k * NC + n]) : (ushort)0;
}

// ---------------- x convert: xpad[NN][128] bf16 (zero-padded K) ----------------
__global__ void convX(const float* __restrict__ x, ushort* __restrict__ xpad) {
    int id = blockIdx.x * blockDim.x + threadIdx.x;
    if (id >= NN * 128) return;
    int n = id >> 7, k = id & 127;
    xpad[id] = (k < FIN) ? f2bf(x[(size_t)n * FIN + k]) : (ushort)0;
}

// ---------------- MFMA bf16 GEMM + fused attention-logit epilogue --------------------
// Cbf[M,NC] bf16 = A[M,K]bf16 @ Wt[NC,K]^T (+bias,relu if BR)
// if AL: al_s[n,h] += sum_c C[n, h*DO_AL+c]*a_s[h,c]  (a_s flat == per-column weight)
// 64x64 tile, 4 waves. A-frag: A[m=lane&15][k=quad*8+j]; B-frag: B[k][n=lane&15];
// D: col=lane&15, row=quad*4+reg  (verified round 2)
template <int K, int NC, bool BR, bool AL>
__launch_bounds__(256)
__global__ void gemm_mfma(const ushort* __restrict__ A, const ushort* __restrict__ Wt,
                          const float* __restrict__ bias, ushort* __restrict__ Cbf,
                          const float* __restrict__ a_s, const float* __restrict__ a_d,
                          float* __restrict__ al_s, float* __restrict__ al_d, int M) {
    constexpr int LDK = K + 8;
    constexpr int DO_AL = NC / H;
    __shared__ ushort As[64 * LDK];
    __shared__ ushort Bs[64 * LDK];
    const int row0 = blockIdx.x * 64;
    const int col0 = blockIdx.y * 64;
    const int tid = threadIdx.x;
    constexpr int CH = K / 8;
    for (int c = tid; c < 64 * CH; c += 256) {
        int r = c / CH, cc = c - r * CH;
        int gr = row0 + r;
        uint4 v = make_uint4(0u, 0u, 0u, 0u);
        if (gr < M) v = *(const uint4*)(A + (size_t)gr * K + cc * 8);
        *(uint4*)(&As[r * LDK + cc * 8]) = v;
        uint4 w = *(const uint4*)(Wt + (size_t)(col0 + r) * K + cc * 8);
        *(uint4*)(&Bs[r * LDK + cc * 8]) = w;
    }
    __syncthreads();
    const int wave = tid >> 6;
    const int lane = tid & 63;
    const int m = lane & 15;
    const int q = lane >> 4;
    f32x4 acc0 = {0.f, 0.f, 0.f, 0.f}, acc1 = acc0, acc2 = acc0, acc3 = acc0;
    const ushort* ap  = &As[(wave * 16 + m) * LDK + q * 8];
    const ushort* bp0 = &Bs[(0 * 16 + m) * LDK + q * 8];
    const ushort* bp1 = &Bs[(1 * 16 + m) * LDK + q * 8];
    const ushort* bp2 = &Bs[(2 * 16 + m) * LDK + q * 8];
    const ushort* bp3 = &Bs[(3 * 16 + m) * LDK + q * 8];
#pragma unroll
    for (int kk = 0; kk < K / 32; kk++) {
        bf16x8 a = *(const bf16x8*)(ap + kk * 32);
        acc0 = __builtin_amdgcn_mfma_f32_16x16x32_bf16(a, *(const bf16x8*)(bp0 + kk * 32), acc0, 0, 0, 0);
        acc1 = __builtin_amdgcn_mfma_f32_16x16x32_bf16(a, *(const bf16x8*)(bp1 + kk * 32), acc1, 0, 0, 0);
        acc2 = __builtin_amdgcn_mfma_f32_16x16x32_bf16(a, *(const bf16x8*)(bp2 + kk * 32), acc2, 0, 0, 0);
        acc3 = __builtin_amdgcn_mfma_f32_16x16x32_bf16(a, *(const bf16x8*)(bp3 + kk * 32), acc3, 0, 0, 0);
    }
    const int grow0 = row0 + wave * 16 + q * 4;
    ushort* Cb = Cbf + (size_t)grow0 * NC + col0 + m;
    float b0 = 0, b1 = 0, b2 = 0, b3 = 0;
    if (BR) {
        b0 = bias[col0 + m];      b1 = bias[col0 + m + 16];
        b2 = bias[col0 + m + 32]; b3 = bias[col0 + m + 48];
    }
#pragma unroll
    for (int r = 0; r < 4; r++) {
        if (grow0 + r < M) {
            float v0 = acc0[r], v1 = acc1[r], v2 = acc2[r], v3 = acc3[r];
            if (BR) {
                v0 = fmaxf(v0 + b0, 0.f); v1 = fmaxf(v1 + b1, 0.f);
                v2 = fmaxf(v2 + b2, 0.f); v3 = fmaxf(v3 + b3, 0.f);
            }
            Cb[(size_t)r * NC + 0]  = f2bf(v0);
            Cb[(size_t)r * NC + 16] = f2bf(v1);
            Cb[(size_t)r * NC + 32] = f2bf(v2);
            Cb[(size_t)r * NC + 48] = f2bf(v3);
        }
    }
    if (AL) {
        // a_s/a_d are [H][DO_AL] flat == [NC]; column gc uses a_s[gc]
        float asv[4], adv[4];
#pragma unroll
        for (int t = 0; t < 4; t++) {
            int gc = col0 + m + 16 * t;
            asv[t] = a_s[gc];
            adv[t] = a_d[gc];
        }
        const int h_lo = col0 / DO_AL;              // head of cols [col0, col0+32)
        const int h_hi = (col0 + 32) / DO_AL;       // head of cols [col0+32, col0+64)
#pragma unroll
        for (int r = 0; r < 4; r++) {
            float ps0 = acc0[r] * asv[0] + acc1[r] * asv[1];
            float ps1 = acc2[r] * asv[2] + acc3[r] * asv[3];
            float pd0 = acc0[r] * adv[0] + acc1[r] * adv[1];
            float pd1 = acc2[r] * adv[2] + acc3[r] * adv[3];
#pragma unroll
            for (int off = 1; off < 16; off <<= 1) {
                ps0 += __shfl_xor(ps0, off);
                ps1 += __shfl_xor(ps1, off);
                pd0 += __shfl_xor(pd0, off);
                pd1 += __shfl_xor(pd1, off);
            }
            if (m == 0 && grow0 + r < M) {
                if (h_lo == h_hi) {
                    atomicAdd(&al_s[(grow0 + r) * H + h_lo], ps0 + ps1);
                    atomicAdd(&al_d[(grow0 + r) * H + h_lo], pd0 + pd1);
                } else {
                    atomicAdd(&al_s[(grow0 + r) * H + h_lo], ps0);
                    atomicAdd(&al_s[(grow0 + r) * H + h_hi], ps1);
                    atomicAdd(&al_d[(grow0 + r) * H + h_lo], pd0);
                    atomicAdd(&al_d[(grow0 + r) * H + h_hi], pd1);
                }
            }
        }
    }
}

// ---------------- fused segment softmax: one wave per dst, writes normalized alpha ----------
__global__ void softmax_csr(const int* __restrict__ rowptr, const int* __restrict__ esrc,
                            const float* __restrict__ al_s, const float* __restrict__ al_d,
                            float4* __restrict__ alpha) {
    int wid = (blockIdx.x * blockDim.x + threadIdx.x) >> 6;
    int lane = threadIdx.x & 63;
    if (wid >= NN) return;
    int p0 = rowptr[wid], p1 = rowptr[wid + 1];
    float4 d4 = ((const float4*)al_d)[wid];
    float m0 = -1e30f, m1 = -1e30f, m2 = -1e30f, m3 = -1e30f;
    for (int p = p0 + lane; p < p1; p += 64) {
        int s = esrc[p];
        float4 s4 = ((const float4*)al_s)[s];
        m0 = fmaxf(m0, lrelu(s4.x + d4.x));
        m1 = fmaxf(m1, lrelu(s4.y + d4.y));
        m2 = fmaxf(m2, lrelu(s4.z + d4.z));
        m3 = fmaxf(m3, lrelu(s4.w + d4.w));
    }
#pragma unroll
    for (int off = 32; off > 0; off >>= 1) {
        m0 = fmaxf(m0, __shfl_xor(m0, off));
        m1 = fmaxf(m1, __shfl_xor(m1, off));
        m2 = fmaxf(m2, __shfl_xor(m2, off));
        m3 = fmaxf(m3, __shfl_xor(m3, off));
    }
    float s0 = 0.f, s1 = 0.f, s2 = 0.f, s3 = 0.f;
    for (int p = p0 + lane; p < p1; p += 64) {
        int s = esrc[p];
        float4 s4 = ((const float4*)al_s)[s];
        s0 += __expf(lrelu(s4.x + d4.x) - m0);
        s1 += __expf(lrelu(s4.y + d4.y) - m1);
        s2 += __expf(lrelu(s4.z + d4.z) - m2);
        s3 += __expf(lrelu(s4.w + d4.w) - m3);
    }
#pragma unroll
    for (int off = 32; off > 0; off >>= 1) {
        s0 += __shfl_xor(s0, off);
        s1 += __shfl_xor(s1, off);
        s2 += __shfl_xor(s2, off);
        s3 += __shfl_xor(s3, off);
    }
    float i0 = 1.f / (s0 + 1e-16f), i1 = 1.f / (s1 + 1e-16f);
    float i2 = 1.f / (s2 + 1e-16f), i3 = 1.f / (s3 + 1e-16f);
    for (int p = p0 + lane; p < p1; p += 64) {
        int s = esrc[p];
        float4 s4 = ((const float4*)al_s)[s];
        alpha[p] = make_float4(__expf(lrelu(s4.x + d4.x) - m0) * i0,
                               __expf(lrelu(s4.y + d4.y) - m1) * i1,
                               __expf(lrelu(s4.z + d4.z) - m2) * i2,
                               __expf(lrelu(s4.w + d4.w) - m3) * i3);
    }
}

// ------- aggregate (uint4 bf16 gather, EPI edges/iter) + head-mean + bias + relu + LN -------
template <int DO, bool RESID>
__launch_bounds__(256)
__global__ void aggregate(const ushort* __restrict__ hproj, const int* __restrict__ rowptr,
                          const int* __restrict__ esrc, const float4* __restrict__ alpha,
                          const float* __restrict__ bias, const float* __restrict__ gamma,
                          const float* __restrict__ beta, const ushort* __restrict__ hprev,
                          ushort* __restrict__ hout) {
    constexpr int HDO = H * DO;
    constexpr int SL  = HDO / 8;        // uint4 slots per row (128/64/32/16)
    constexpr int EPI = 256 / SL;       // edges per iteration (2/4/8/16)
    constexpr int DO2 = DO / 2;
    __shared__ float part[256 * 8];     // [EPI][HDO] flattened == [tid*8+j], 8 KB
    __shared__ float red[256];
    const int n = blockIdx.x;
    const int tid = threadIdx.x;
    const int e = tid / SL;
    const int s = tid - e * SL;
    const int head = (s * 8) / DO;
    const int p0 = rowptr[n], p1 = rowptr[n + 1];
    const uint4* hp4 = (const uint4*)hproj;

    float acc[8];
#pragma unroll
    for (int j = 0; j < 8; j++) acc[j] = 0.f;

    int p = p0 + e;
    if (p < p1) {
        int src = esrc[p];
        float4 al4 = alpha[p];
        while (true) {
            int pn = p + EPI;
            bool more = (pn < p1);
            int srcn = 0;
            float4 aln = make_float4(0.f, 0.f, 0.f, 0.f);
            if (more) { srcn = esrc[pn]; aln = alpha[pn]; }
            uint4 v = hp4[(size_t)src * SL + s];
            float a = (head == 0) ? al4.x : (head == 1) ? al4.y : (head == 2) ? al4.z : al4.w;
            acc[0] += a * bf_lo(v.x); acc[1] += a * bf_hi(v.x);
            acc[2] += a * bf_lo(v.y); acc[3] += a * bf_hi(v.y);
            acc[4] += a * bf_lo(v.z); acc[5] += a * bf_hi(v.z);
            acc[6] += a * bf_lo(v.w); acc[7] += a * bf_hi(v.w);
            if (!more) break;
            p = pn; src = srcn; al4 = aln;
        }
    }
#pragma unroll
    for (int j = 0; j < 8; j++) part[tid * 8 + j] = acc[j];
    __syncthreads();
    // combine across edge groups e: channel c owner = thread c (mod 256)
    for (int c = tid; c < HDO; c += 256) {
        float v = part[c];
#pragma unroll
        for (int ee = 1; ee < EPI; ee++) v += part[ee * HDO + c];
        part[c] = v;
    }
    __syncthreads();
    float v0 = 0.f, v1 = 0.f;
    if (tid < DO2) {
#pragma unroll
        for (int h = 0; h < H; h++) {
            v0 += part[h * DO + 2 * tid];
            v1 += part[h * DO + 2 * tid + 1];
        }
        v0 = fmaxf(0.25f * v0 + bias[2 * tid], 0.f);
        v1 = fmaxf(0.25f * v1 + bias[2 * tid + 1], 0.f);
    }
    red[tid] = (tid < DO2) ? (v0 + v1) : 0.f;
    __syncthreads();
    for (int off = 128; off > 0; off >>= 1) {
        if (tid < off) red[tid] += red[tid + off];
        __syncthreads();
    }
    float mu = red[0] / DO;
    __syncthreads();
    float d0 = v0 - mu, d1 = v1 - mu;
    red[tid] = (tid < DO2) ? (d0 * d0 + d1 * d1) : 0.f;
    __syncthreads();
    for (int off = 128; off > 0; off >>= 1) {
        if (tid < off) red[tid] += red[tid + off];
        __syncthreads();
    }
    float rstd = rsqrtf(red[0] / DO + LN_EPS);
    if (tid < DO2) {
        float o0 = d0 * rstd * gamma[2 * tid]     + beta[2 * tid];
        float o1 = d1 * rstd * gamma[2 * tid + 1] + beta[2 * tid + 1];
        if (RESID) {
            unsigned pv = ((const unsigned*)(hprev + (size_t)n * DO))[tid];
            o0 += bf_lo(pv);
            o1 += bf_hi(pv) * 1.0f;  // hi half is already the float value
        }
        unsigned ob = (unsigned)f2bf(o0) | ((unsigned)f2bf(o1) << 16);
        ((unsigned*)(hout + (size_t)n * DO))[tid] = ob;
    }
}

// ---------------- pooling (hierarchical) + readout ----------------
__global__ void pool_accum2(const ushort* __restrict__ h, const int* __restrict__ batch,
                            float* __restrict__ pooled, float* __restrict__ cnt) {
    __shared__ float lp[BG * 32];
    __shared__ float lc[BG];
    for (int i = threadIdx.x; i < BG * 32; i += blockDim.x) lp[i] = 0.f;
    if (threadIdx.x < BG) lc[threadIdx.x] = 0.f;
    __syncthreads();
    int c = threadIdx.x & 31;
    int rb = threadIdx.x >> 5;
    for (int n = blockIdx.x * 8 + rb; n < NN; n += gridDim.x * 8) {
        int b = batch[n];
        atomicAdd(&lp[b * 32 + c], bf2f((unsigned)h[(size_t)n * 32 + c]));
        if (c == 0) atomicAdd(&lc[b], 1.f);
    }
    __syncthreads();
    for (int i = threadIdx.x; i < BG * 32; i += blockDim.x) atomicAdd(&pooled[i], lp[i]);
    if (threadIdx.x < BG) atomicAdd(&cnt[threadIdx.x], lc[threadIdx.x]);
}

__global__ void final_out(const float* __restrict__ pooled, const float* __restrict__ cnt,
                          const float* __restrict__ Wo, const float* __restrict__ bo,
                          float* __restrict__ out) {
    int b = threadIdx.x;
    if (b < BG) {
        float inv = 1.f / fmaxf(cnt[b], 1.f);
        float acc = 0.f;
        for (int c = 0; c < 32; c++) acc += pooled[b * 32 + c] * inv * Wo[c];
        out[b] = acc + bo[0];
    }
}

// ---------------- host orchestration ----------------
extern "C" void kernel_launch(void* const* d_in, const int* in_sizes, int n_in,
                              void* d_out, int out_size, void* d_ws, size_t ws_size,
                              hipStream_t stream) {
    const float* x     = (const float*)d_in[0];
    const int*   ei    = (const int*)d_in[1];
    const int*   batch = (const int*)d_in[2];
    const float* Wi    = (const float*)d_in[3];
    const float* bi    = (const float*)d_in[4];
    const float* Wl[4]  = {(const float*)d_in[5],  (const float*)d_in[11], (const float*)d_in[17], (const float*)d_in[23]};
    const float* Asl[4] = {(const float*)d_in[6],  (const float*)d_in[12], (const float*)d_in[18], (const float*)d_in[24]};
    const float* Adl[4] = {(const float*)d_in[7],  (const float*)d_in[13], (const float*)d_in[19], (const float*)d_in[25]};
    const float* Bl[4]  = {(const float*)d_in[8],  (const float*)d_in[14], (const float*)d_in[20], (const float*)d_in[26]};
    const float* Gl[4]  = {(const float*)d_in[9],  (const float*)d_in[15], (const float*)d_in[21], (const float*)d_in[27]};
    const float* Bel[4] = {(const float*)d_in[10], (const float*)d_in[16], (const float*)d_in[22], (const float*)d_in[28]};
    const float* Wo = (const float*)d_in[29];
    const float* bo = (const float*)d_in[30];

    char* p = (char*)d_ws;
    auto take = [&](size_t bytes) -> void* {
        void* r = (void*)p;
        p += (bytes + 255) & ~(size_t)255;
        return r;
    };
    ushort*   hAbf   = (ushort*)take((size_t)NN * HID * 2);
    ushort*   hBbf   = (ushort*)take((size_t)NN * HID * 2);
    ushort*   hproj  = (ushort*)take((size_t)NN * H * HID * 2);
    ushort*   xpad   = (ushort*)take((size_t)NN * 128 * 2);
    float*    al_s   = (float*)take((size_t)NN * H * 4);   // adjacent to al_d (320000 B, 256-mult)
    float*    al_d   = (float*)take((size_t)NN * H * 4);
    float4*   alpha  = (float4*)take((size_t)ETOT * 16);
    int*      deg    = (int*)take((size_t)NN * 4);
    int*      fill   = (int*)take((size_t)NN * 4);
    int*      rowptr = (int*)take((size_t)(NN + 1) * 4);
    int*      esrc   = (int*)take((size_t)ETOT * 4);
    float*    pooled = (float*)take((size_t)BG * 32 * 4);
    float*    cnt    = (float*)take((size_t)BG * 4);
    ushort*   wti    = (ushort*)take((size_t)256 * 128 * 2);
    ushort*   wt0    = (ushort*)take((size_t)1024 * 256 * 2);
    ushort*   wt1    = (ushort*)take((size_t)512 * 256 * 2);
    ushort*   wt2    = (ushort*)take((size_t)256 * 128 * 2);
    ushort*   wt3    = (ushort*)take((size_t)128 * 64 * 2);
    (void)ws_size; (void)n_in; (void)in_sizes; (void)out_size;

    const int ZB = 256;
    const int egrid = (ETOT + ZB - 1) / ZB;
    const int mtiles = (NN + 63) / 64;       // 313
    const int algrid = (2 * NN * H + ZB - 1) / ZB;

    // zero: deg, fill, pooled+cnt
    zero_u32<<<(NN + ZB - 1) / ZB, ZB, 0, stream>>>((uint32_t*)deg, NN);
    zero_u32<<<(NN + ZB - 1) / ZB, ZB, 0, stream>>>((uint32_t*)fill, NN);
    zero_u32<<<2, ZB, 0, stream>>>((uint32_t*)pooled, BG * 32 + BG);

    // weight conversion (bf16, transposed; input weight K-padded 100->128)
    convW<FIN, 128, 256><<<(256 * 128 + 255) / 256, 256, 0, stream>>>(Wi, wti);
    convW<256, 256, 1024><<<(1024 * 256 + 255) / 256, 256, 0, stream>>>(Wl[0], wt0);
    convW<256, 256, 512><<<(512 * 256 + 255) / 256, 256, 0, stream>>>(Wl[1], wt1);
    convW<128, 128, 256><<<(256 * 128 + 255) / 256, 256, 0, stream>>>(Wl[2], wt2);
    convW<64, 64, 128><<<(128 * 64 + 255) / 256, 256, 0, stream>>>(Wl[3], wt3);
    convX<<<(NN * 128 + 255) / 256, 256, 0, stream>>>(x, xpad);

    // CSR by dst
    count_deg<<<egrid, ZB, 0, stream>>>(ei, deg);
    scan_kernel<<<1, 1024, 0, stream>>>(deg, rowptr);
    scatter_edges<<<egrid, ZB, 0, stream>>>(ei, rowptr, fill, esrc);

    const int sgrid = (NN * 64 + 255) / 256;  // softmax: 1 wave per dst

    // input layer: hAbf = relu(x @ Wi + bi)
    gemm_mfma<128, 256, true, false><<<dim3(mtiles, 4), 256, 0, stream>>>(
        xpad, wti, bi, hAbf, nullptr, nullptr, nullptr, nullptr, NN);

    // ---- level 0: 256 -> 256, residual ----
    zero_u32<<<algrid, ZB, 0, stream>>>((uint32_t*)al_s, 2 * NN * H);
    gemm_mfma<256, 1024, false, true><<<dim3(mtiles, 16), 256, 0, stream>>>(
        hAbf, wt0, nullptr, hproj, Asl[0], Adl[0], al_s, al_d, NN);
    softmax_csr<<<sgrid, 256, 0, stream>>>(rowptr, esrc, al_s, al_d, alpha);
    aggregate<256, true><<<NN, 256, 0, stream>>>(hproj, rowptr, esrc, alpha,
                                                 Bl[0], Gl[0], Bel[0], hAbf, hBbf);
    // ---- level 1: 256 -> 128 ----
    zero_u32<<<algrid, ZB, 0, stream>>>((uint32_t*)al_s, 2 * NN * H);
    gemm_mfma<256, 512, false, true><<<dim3(mtiles, 8), 256, 0, stream>>>(
        hBbf, wt1, nullptr, hproj, Asl[1], Adl[1], al_s, al_d, NN);
    softmax_csr<<<sgrid, 256, 0, stream>>>(rowptr, esrc, al_s, al_d, alpha);
    aggregate<128, false><<<NN, 256, 0, stream>>>(hproj, rowptr, esrc, alpha,
                                                  Bl[1], Gl[1], Bel[1], nullptr, hAbf);
    // ---- level 2: 128 -> 64 ----
    zero_u32<<<algrid, ZB, 0, stream>>>((uint32_t*)al_s, 2 * NN * H);
    gemm_mfma<128, 256, false, true><<<dim3(mtiles, 4), 256, 0, stream>>>(
        hAbf, wt2, nullptr, hproj, Asl[2], Adl[2], al_s, al_d, NN);
    softmax_csr<<<sgrid, 256, 0, stream>>>(rowptr, esrc, al_s, al_d, alpha);
    aggregate<64, false><<<NN, 256, 0, stream>>>(hproj, rowptr, esrc, alpha,
                                                 Bl[2], Gl[2], Bel[2], nullptr, hBbf);
    // ---- level 3: 64 -> 32 ----
    zero_u32<<<algrid, ZB, 0, stream>>>((uint32_t*)al_s, 2 * NN * H);
    gemm_mfma<64, 128, false, true><<<dim3(mtiles, 2), 256, 0, stream>>>(
        hBbf, wt3, nullptr, hproj, Asl[3], Adl[3], al_s, al_d, NN);
    softmax_csr<<<sgrid, 256, 0, stream>>>(rowptr, esrc, al_s, al_d, alpha);
    aggregate<32, false><<<NN, 256, 0, stream>>>(hproj, rowptr, esrc, alpha,
                                                 Bl[3], Gl[3], Bel[3], nullptr, hAbf);

    // ---- pooling + readout ----
    pool_accum2<<<80, 256, 0, stream>>>(hAbf, batch, pooled, cnt);
    final_out<<<1, 64, 0, stream>>>(pooled, cnt, Wo, bo, (float*)d_out);
}

// Round 5
// 634.187 us; speedup vs baseline: 3.0330x; 1.0610x over previous
//
#include <hip/hip_runtime.h>
#include <hip/hip_bf16.h>
#include <cstdint>

// ---- problem constants (HierarchicalBrainGNN) ----
constexpr int NN   = 20000;          // nodes
constexpr int NE   = 320000;         // edges before self loops
constexpr int ETOT = NE + NN;        // with self loops
constexpr int BG   = 8;              // graphs
constexpr int FIN  = 100;
constexpr int HID  = 256;
constexpr int H    = 4;              // heads
constexpr float SLOPE  = 0.2f;
constexpr float LN_EPS = 1e-5f;

#define DEVFN __device__ __forceinline__

typedef __bf16 bf16x8 __attribute__((ext_vector_type(8)));
typedef float  f32x4  __attribute__((ext_vector_type(4)));
typedef float  f32x2  __attribute__((ext_vector_type(2)));

DEVFN float lrelu(float v) { return v > 0.f ? v : SLOPE * v; }
// fp32 -> bf16 bits, round-nearest-even (finite inputs)
DEVFN ushort f2bf(float f) {
    unsigned u = __float_as_uint(f);
    return (ushort)((u + 0x7fffu + ((u >> 16) & 1u)) >> 16);
}
DEVFN float bf_lo(unsigned u) { return __uint_as_float(u << 16); }
DEVFN float bf_hi(unsigned u) { return __uint_as_float(u & 0xffff0000u); }
DEVFN float bf2f(unsigned u) { return __uint_as_float(u << 16); }

// ---------------- utility ----------------
__global__ void zero_u32(uint32_t* __restrict__ p, int n) {
    int i = blockIdx.x * blockDim.x + threadIdx.x;
    if (i < n) p[i] = 0u;
}

// ---------------- CSR build ----------------
__global__ void count_deg(const int* __restrict__ ei, int* __restrict__ deg) {
    int k = blockIdx.x * blockDim.x + threadIdx.x;
    if (k >= ETOT) return;
    int d = (k < NE) ? ei[NE + k] : (k - NE);
    atomicAdd(&deg[d], 1);
}

__global__ void scan_kernel(const int* __restrict__ deg, int* __restrict__ rowptr) {
    __shared__ int buf[1024];
    int carry = 0;
    for (int base = 0; base < NN; base += 1024) {
        int i = base + threadIdx.x;
        int v = (i < NN) ? deg[i] : 0;
        buf[threadIdx.x] = v;
        __syncthreads();
        for (int off = 1; off < 1024; off <<= 1) {
            int t = (threadIdx.x >= off) ? buf[threadIdx.x - off] : 0;
            __syncthreads();
            buf[threadIdx.x] += t;
            __syncthreads();
        }
        int incl = buf[threadIdx.x];
        if (i < NN) rowptr[i] = carry + incl - v;   // exclusive prefix
        int total = buf[1023];
        __syncthreads();
        carry += total;
    }
    if (threadIdx.x == 0) rowptr[NN] = carry;
}

__global__ void scatter_edges(const int* __restrict__ ei, const int* __restrict__ rowptr,
                              int* __restrict__ fill, int* __restrict__ esrc) {
    int k = blockIdx.x * blockDim.x + threadIdx.x;
    if (k >= ETOT) return;
    int s, d;
    if (k < NE) { s = ei[k]; d = ei[NE + k]; }
    else        { s = k - NE; d = k - NE; }
    int pos = rowptr[d] + atomicAdd(&fill[d], 1);
    esrc[pos] = s;
}

// ---------------- weight convert+transpose: Wt[NC][KP] bf16 from W[KS][NC] fp32 ----------------
template <int KS, int KP, int NC>
__global__ void convW(const float* __restrict__ W, ushort* __restrict__ Wt) {
    int id = blockIdx.x * blockDim.x + threadIdx.x;
    if (id >= NC * KP) return;
    int n = id / KP, k = id - n * KP;
    Wt[id] = (k < KS) ? f2bf(W[(size_t)k * NC + n]) : (ushort)0;
}

// ---------------- x convert: xpad[NN][128] bf16 (zero-padded K) ----------------
__global__ void convX(const float* __restrict__ x, ushort* __restrict__ xpad) {
    int id = blockIdx.x * blockDim.x + threadIdx.x;
    if (id >= NN * 128) return;
    int n = id >> 7, k = id & 127;
    xpad[id] = (k < FIN) ? f2bf(x[(size_t)n * FIN + k]) : (ushort)0;
}

// ---------------- MFMA bf16 GEMM + fused attention-logit epilogue --------------------
// if !AL: Cout = bf16[M,NC] = relu(A@Wt^T + bias) (input layer)
// if  AL: Cout = fp8 e4m3 [M,NC] (hproj, consumed only by aggregate gather);
//         al_s[n,h] += sum_c C[n,h*DO+c]*a_s[h,c] from fp32 accs (exact logits)
// 64x64 tile, 4 waves. A-frag: A[m=lane&15][k=quad*8+j]; B-frag: B[k][n=lane&15];
// D: col=lane&15, row=quad*4+reg  (verified round 2)
template <int K, int NC, bool BR, bool AL>
__launch_bounds__(256)
__global__ void gemm_mfma(const ushort* __restrict__ A, const ushort* __restrict__ Wt,
                          const float* __restrict__ bias, void* __restrict__ Cout,
                          const float* __restrict__ a_s, const float* __restrict__ a_d,
                          float* __restrict__ al_s, float* __restrict__ al_d, int M) {
    constexpr int LDK = K + 8;
    constexpr int DO_AL = NC / H;
    __shared__ ushort As[64 * LDK];
    __shared__ ushort Bs[64 * LDK];
    const int row0 = blockIdx.x * 64;
    const int col0 = blockIdx.y * 64;
    const int tid = threadIdx.x;
    constexpr int CH = K / 8;
    for (int c = tid; c < 64 * CH; c += 256) {
        int r = c / CH, cc = c - r * CH;
        int gr = row0 + r;
        uint4 v = make_uint4(0u, 0u, 0u, 0u);
        if (gr < M) v = *(const uint4*)(A + (size_t)gr * K + cc * 8);
        *(uint4*)(&As[r * LDK + cc * 8]) = v;
        uint4 w = *(const uint4*)(Wt + (size_t)(col0 + r) * K + cc * 8);
        *(uint4*)(&Bs[r * LDK + cc * 8]) = w;
    }
    __syncthreads();
    const int wave = tid >> 6;
    const int lane = tid & 63;
    const int m = lane & 15;
    const int q = lane >> 4;
    f32x4 acc0 = {0.f, 0.f, 0.f, 0.f}, acc1 = acc0, acc2 = acc0, acc3 = acc0;
    const ushort* ap  = &As[(wave * 16 + m) * LDK + q * 8];
    const ushort* bp0 = &Bs[(0 * 16 + m) * LDK + q * 8];
    const ushort* bp1 = &Bs[(1 * 16 + m) * LDK + q * 8];
    const ushort* bp2 = &Bs[(2 * 16 + m) * LDK + q * 8];
    const ushort* bp3 = &Bs[(3 * 16 + m) * LDK + q * 8];
#pragma unroll
    for (int kk = 0; kk < K / 32; kk++) {
        bf16x8 a = *(const bf16x8*)(ap + kk * 32);
        acc0 = __builtin_amdgcn_mfma_f32_16x16x32_bf16(a, *(const bf16x8*)(bp0 + kk * 32), acc0, 0, 0, 0);
        acc1 = __builtin_amdgcn_mfma_f32_16x16x32_bf16(a, *(const bf16x8*)(bp1 + kk * 32), acc1, 0, 0, 0);
        acc2 = __builtin_amdgcn_mfma_f32_16x16x32_bf16(a, *(const bf16x8*)(bp2 + kk * 32), acc2, 0, 0, 0);
        acc3 = __builtin_amdgcn_mfma_f32_16x16x32_bf16(a, *(const bf16x8*)(bp3 + kk * 32), acc3, 0, 0, 0);
    }
    const int grow0 = row0 + wave * 16 + q * 4;
    if (!AL) {
        ushort* Cb = (ushort*)Cout + (size_t)grow0 * NC + col0 + m;
        float b0 = 0, b1 = 0, b2 = 0, b3 = 0;
        if (BR) {
            b0 = bias[col0 + m];      b1 = bias[col0 + m + 16];
            b2 = bias[col0 + m + 32]; b3 = bias[col0 + m + 48];
        }
#pragma unroll
        for (int r = 0; r < 4; r++) {
            if (grow0 + r < M) {
                float v0 = acc0[r], v1 = acc1[r], v2 = acc2[r], v3 = acc3[r];
                if (BR) {
                    v0 = fmaxf(v0 + b0, 0.f); v1 = fmaxf(v1 + b1, 0.f);
                    v2 = fmaxf(v2 + b2, 0.f); v3 = fmaxf(v3 + b3, 0.f);
                }
                Cb[(size_t)r * NC + 0]  = f2bf(v0);
                Cb[(size_t)r * NC + 16] = f2bf(v1);
                Cb[(size_t)r * NC + 32] = f2bf(v2);
                Cb[(size_t)r * NC + 48] = f2bf(v3);
            }
        }
    } else {
        uchar* Cb = (uchar*)Cout + (size_t)grow0 * NC + col0 + m;
#pragma unroll
        for (int r = 0; r < 4; r++) {
            if (grow0 + r < M) {
                int pk01 = __builtin_amdgcn_cvt_pk_fp8_f32(acc0[r], acc1[r], 0, false);
                int pk23 = __builtin_amdgcn_cvt_pk_fp8_f32(acc2[r], acc3[r], 0, false);
                Cb[(size_t)r * NC + 0]  = (uchar)(pk01 & 0xff);
                Cb[(size_t)r * NC + 16] = (uchar)((pk01 >> 8) & 0xff);
                Cb[(size_t)r * NC + 32] = (uchar)(pk23 & 0xff);
                Cb[(size_t)r * NC + 48] = (uchar)((pk23 >> 8) & 0xff);
            }
        }
        // fused attention logits from exact fp32 accumulators
        float asv[4], adv[4];
#pragma unroll
        for (int t = 0; t < 4; t++) {
            int gc = col0 + m + 16 * t;
            asv[t] = a_s[gc];
            adv[t] = a_d[gc];
        }
        const int h_lo = col0 / DO_AL;
        const int h_hi = (col0 + 32) / DO_AL;
#pragma unroll
        for (int r = 0; r < 4; r++) {
            float ps0 = acc0[r] * asv[0] + acc1[r] * asv[1];
            float ps1 = acc2[r] * asv[2] + acc3[r] * asv[3];
            float pd0 = acc0[r] * adv[0] + acc1[r] * adv[1];
            float pd1 = acc2[r] * adv[2] + acc3[r] * adv[3];
#pragma unroll
            for (int off = 1; off < 16; off <<= 1) {
                ps0 += __shfl_xor(ps0, off);
                ps1 += __shfl_xor(ps1, off);
                pd0 += __shfl_xor(pd0, off);
                pd1 += __shfl_xor(pd1, off);
            }
            if (m == 0 && grow0 + r < M) {
                if (h_lo == h_hi) {
                    atomicAdd(&al_s[(grow0 + r) * H + h_lo], ps0 + ps1);
                    atomicAdd(&al_d[(grow0 + r) * H + h_lo], pd0 + pd1);
                } else {
                    atomicAdd(&al_s[(grow0 + r) * H + h_lo], ps0);
                    atomicAdd(&al_s[(grow0 + r) * H + h_hi], ps1);
                    atomicAdd(&al_d[(grow0 + r) * H + h_lo], pd0);
                    atomicAdd(&al_d[(grow0 + r) * H + h_hi], pd1);
                }
            }
        }
    }
}

// ---------------- fused segment softmax: one wave per dst, writes normalized alpha ----------
__global__ void softmax_csr(const int* __restrict__ rowptr, const int* __restrict__ esrc,
                            const float* __restrict__ al_s, const float* __restrict__ al_d,
                            float4* __restrict__ alpha) {
    int wid = (blockIdx.x * blockDim.x + threadIdx.x) >> 6;
    int lane = threadIdx.x & 63;
    if (wid >= NN) return;
    int p0 = rowptr[wid], p1 = rowptr[wid + 1];
    float4 d4 = ((const float4*)al_d)[wid];
    float m0 = -1e30f, m1 = -1e30f, m2 = -1e30f, m3 = -1e30f;
    for (int p = p0 + lane; p < p1; p += 64) {
        int s = esrc[p];
        float4 s4 = ((const float4*)al_s)[s];
        m0 = fmaxf(m0, lrelu(s4.x + d4.x));
        m1 = fmaxf(m1, lrelu(s4.y + d4.y));
        m2 = fmaxf(m2, lrelu(s4.z + d4.z));
        m3 = fmaxf(m3, lrelu(s4.w + d4.w));
    }
#pragma unroll
    for (int off = 32; off > 0; off >>= 1) {
        m0 = fmaxf(m0, __shfl_xor(m0, off));
        m1 = fmaxf(m1, __shfl_xor(m1, off));
        m2 = fmaxf(m2, __shfl_xor(m2, off));
        m3 = fmaxf(m3, __shfl_xor(m3, off));
    }
    float s0 = 0.f, s1 = 0.f, s2 = 0.f, s3 = 0.f;
    for (int p = p0 + lane; p < p1; p += 64) {
        int s = esrc[p];
        float4 s4 = ((const float4*)al_s)[s];
        s0 += __expf(lrelu(s4.x + d4.x) - m0);
        s1 += __expf(lrelu(s4.y + d4.y) - m1);
        s2 += __expf(lrelu(s4.z + d4.z) - m2);
        s3 += __expf(lrelu(s4.w + d4.w) - m3);
    }
#pragma unroll
    for (int off = 32; off > 0; off >>= 1) {
        s0 += __shfl_xor(s0, off);
        s1 += __shfl_xor(s1, off);
        s2 += __shfl_xor(s2, off);
        s3 += __shfl_xor(s3, off);
    }
    float i0 = 1.f / (s0 + 1e-16f), i1 = 1.f / (s1 + 1e-16f);
    float i2 = 1.f / (s2 + 1e-16f), i3 = 1.f / (s3 + 1e-16f);
    for (int p = p0 + lane; p < p1; p += 64) {
        int s = esrc[p];
        float4 s4 = ((const float4*)al_s)[s];
        alpha[p] = make_float4(__expf(lrelu(s4.x + d4.x) - m0) * i0,
                               __expf(lrelu(s4.y + d4.y) - m1) * i1,
                               __expf(lrelu(s4.z + d4.z) - m2) * i2,
                               __expf(lrelu(s4.w + d4.w) - m3) * i3);
    }
}

// ------- aggregate (fp8 uint4 gather = 16ch/lane) + head-mean + bias + relu + LN ----------
template <int DO, bool RESID>
__launch_bounds__(256)
__global__ void aggregate(const uchar* __restrict__ hproj, const int* __restrict__ rowptr,
                          const int* __restrict__ esrc, const float4* __restrict__ alpha,
                          const float* __restrict__ bias, const float* __restrict__ gamma,
                          const float* __restrict__ beta, const ushort* __restrict__ hprev,
                          ushort* __restrict__ hout) {
    constexpr int HDO = H * DO;
    constexpr int SL  = HDO / 16;       // uint4 slots per row (16 fp8 each)
    constexpr int EPI = 256 / SL;       // edges per iteration (4/8/16/32)
    constexpr int DO2 = DO / 2;
    __shared__ float part[256 * 16];    // [EPI][HDO] flattened, 16 KB
    __shared__ float red[256];
    const int n = blockIdx.x;
    const int tid = threadIdx.x;
    const int e = tid / SL;
    const int s = tid - e * SL;
    const int head = (s * 16) / DO;
    const int p0 = rowptr[n], p1 = rowptr[n + 1];
    const uint4* hp4 = (const uint4*)hproj;

    float acc[16];
#pragma unroll
    for (int j = 0; j < 16; j++) acc[j] = 0.f;

    int p = p0 + e;
    if (p < p1) {
        int src = esrc[p];
        float4 al4 = alpha[p];
        while (true) {
            int pn = p + EPI;
            bool more = (pn < p1);
            int srcn = 0;
            float4 aln = make_float4(0.f, 0.f, 0.f, 0.f);
            if (more) { srcn = esrc[pn]; aln = alpha[pn]; }
            uint4 v = hp4[(size_t)src * SL + s];
            float a = (head == 0) ? al4.x : (head == 1) ? al4.y : (head == 2) ? al4.z : al4.w;
            f32x2 d;
            d = __builtin_amdgcn_cvt_pk_f32_fp8(v.x, false); acc[0]  += a * d[0]; acc[1]  += a * d[1];
            d = __builtin_amdgcn_cvt_pk_f32_fp8(v.x, true);  acc[2]  += a * d[0]; acc[3]  += a * d[1];
            d = __builtin_amdgcn_cvt_pk_f32_fp8(v.y, false); acc[4]  += a * d[0]; acc[5]  += a * d[1];
            d = __builtin_amdgcn_cvt_pk_f32_fp8(v.y, true);  acc[6]  += a * d[0]; acc[7]  += a * d[1];
            d = __builtin_amdgcn_cvt_pk_f32_fp8(v.z, false); acc[8]  += a * d[0]; acc[9]  += a * d[1];
            d = __builtin_amdgcn_cvt_pk_f32_fp8(v.z, true);  acc[10] += a * d[0]; acc[11] += a * d[1];
            d = __builtin_amdgcn_cvt_pk_f32_fp8(v.w, false); acc[12] += a * d[0]; acc[13] += a * d[1];
            d = __builtin_amdgcn_cvt_pk_f32_fp8(v.w, true);  acc[14] += a * d[0]; acc[15] += a * d[1];
            if (!more) break;
            p = pn; src = srcn; al4 = aln;
        }
    }
#pragma unroll
    for (int j = 0; j < 16; j++) part[tid * 16 + j] = acc[j];
    __syncthreads();
    // combine across edge groups
    for (int c = tid; c < HDO; c += 256) {
        float v = part[c];
#pragma unroll
        for (int ee = 1; ee < EPI; ee++) v += part[ee * HDO + c];
        part[c] = v;
    }
    __syncthreads();
    float v0 = 0.f, v1 = 0.f;
    if (tid < DO2) {
#pragma unroll
        for (int h = 0; h < H; h++) {
            v0 += part[h * DO + 2 * tid];
            v1 += part[h * DO + 2 * tid + 1];
        }
        v0 = fmaxf(0.25f * v0 + bias[2 * tid], 0.f);
        v1 = fmaxf(0.25f * v1 + bias[2 * tid + 1], 0.f);
    }
    red[tid] = (tid < DO2) ? (v0 + v1) : 0.f;
    __syncthreads();
    for (int off = 128; off > 0; off >>= 1) {
        if (tid < off) red[tid] += red[tid + off];
        __syncthreads();
    }
    float mu = red[0] / DO;
    __syncthreads();
    float d0 = v0 - mu, d1 = v1 - mu;
    red[tid] = (tid < DO2) ? (d0 * d0 + d1 * d1) : 0.f;
    __syncthreads();
    for (int off = 128; off > 0; off >>= 1) {
        if (tid < off) red[tid] += red[tid + off];
        __syncthreads();
    }
    float rstd = rsqrtf(red[0] / DO + LN_EPS);
    if (tid < DO2) {
        float o0 = d0 * rstd * gamma[2 * tid]     + beta[2 * tid];
        float o1 = d1 * rstd * gamma[2 * tid + 1] + beta[2 * tid + 1];
        if (RESID) {
            unsigned pv = ((const unsigned*)(hprev + (size_t)n * DO))[tid];
            o0 += bf_lo(pv);
            o1 += bf_hi(pv);
        }
        unsigned ob = (unsigned)f2bf(o0) | ((unsigned)f2bf(o1) << 16);
        ((unsigned*)(hout + (size_t)n * DO))[tid] = ob;
    }
}

// ---------------- pooling (hierarchical) + readout ----------------
__global__ void pool_accum2(const ushort* __restrict__ h, const int* __restrict__ batch,
                            float* __restrict__ pooled, float* __restrict__ cnt) {
    __shared__ float lp[BG * 32];
    __shared__ float lc[BG];
    for (int i = threadIdx.x; i < BG * 32; i += blockDim.x) lp[i] = 0.f;
    if (threadIdx.x < BG) lc[threadIdx.x] = 0.f;
    __syncthreads();
    int c = threadIdx.x & 31;
    int rb = threadIdx.x >> 5;
    for (int n = blockIdx.x * 8 + rb; n < NN; n += gridDim.x * 8) {
        int b = batch[n];
        atomicAdd(&lp[b * 32 + c], bf2f((unsigned)h[(size_t)n * 32 + c]));
        if (c == 0) atomicAdd(&lc[b], 1.f);
    }
    __syncthreads();
    for (int i = threadIdx.x; i < BG * 32; i += blockDim.x) atomicAdd(&pooled[i], lp[i]);
    if (threadIdx.x < BG) atomicAdd(&cnt[threadIdx.x], lc[threadIdx.x]);
}

__global__ void final_out(const float* __restrict__ pooled, const float* __restrict__ cnt,
                          const float* __restrict__ Wo, const float* __restrict__ bo,
                          float* __restrict__ out) {
    int b = threadIdx.x;
    if (b < BG) {
        float inv = 1.f / fmaxf(cnt[b], 1.f);
        float acc = 0.f;
        for (int c = 0; c < 32; c++) acc += pooled[b * 32 + c] * inv * Wo[c];
        out[b] = acc + bo[0];
    }
}

// ---------------- host orchestration ----------------
extern "C" void kernel_launch(void* const* d_in, const int* in_sizes, int n_in,
                              void* d_out, int out_size, void* d_ws, size_t ws_size,
                              hipStream_t stream) {
    const float* x     = (const float*)d_in[0];
    const int*   ei    = (const int*)d_in[1];
    const int*   batch = (const int*)d_in[2];
    const float* Wi    = (const float*)d_in[3];
    const float* bi    = (const float*)d_in[4];
    const float* Wl[4]  = {(const float*)d_in[5],  (const float*)d_in[11], (const float*)d_in[17], (const float*)d_in[23]};
    const float* Asl[4] = {(const float*)d_in[6],  (const float*)d_in[12], (const float*)d_in[18], (const float*)d_in[24]};
    const float* Adl[4] = {(const float*)d_in[7],  (const float*)d_in[13], (const float*)d_in[19], (const float*)d_in[25]};
    const float* Bl[4]  = {(const float*)d_in[8],  (const float*)d_in[14], (const float*)d_in[20], (const float*)d_in[26]};
    const float* Gl[4]  = {(const float*)d_in[9],  (const float*)d_in[15], (const float*)d_in[21], (const float*)d_in[27]};
    const float* Bel[4] = {(const float*)d_in[10], (const float*)d_in[16], (const float*)d_in[22], (const float*)d_in[28]};
    const float* Wo = (const float*)d_in[29];
    const float* bo = (const float*)d_in[30];

    char* p = (char*)d_ws;
    auto take = [&](size_t bytes) -> void* {
        void* r = (void*)p;
        p += (bytes + 255) & ~(size_t)255;
        return r;
    };
    ushort*   hAbf   = (ushort*)take((size_t)NN * HID * 2);
    ushort*   hBbf   = (ushort*)take((size_t)NN * HID * 2);
    uchar*    hproj  = (uchar*)take((size_t)NN * H * HID);      // fp8 e4m3
    ushort*   xpad   = (ushort*)take((size_t)NN * 128 * 2);
    float*    al_s   = (float*)take((size_t)NN * H * 4);   // adjacent to al_d
    float*    al_d   = (float*)take((size_t)NN * H * 4);
    float4*   alpha  = (float4*)take((size_t)ETOT * 16);
    int*      deg    = (int*)take((size_t)NN * 4);
    int*      fill   = (int*)take((size_t)NN * 4);
    int*      rowptr = (int*)take((size_t)(NN + 1) * 4);
    int*      esrc   = (int*)take((size_t)ETOT * 4);
    float*    pooled = (float*)take((size_t)BG * 32 * 4);
    float*    cnt    = (float*)take((size_t)BG * 4);
    ushort*   wti    = (ushort*)take((size_t)256 * 128 * 2);
    ushort*   wt0    = (ushort*)take((size_t)1024 * 256 * 2);
    ushort*   wt1    = (ushort*)take((size_t)512 * 256 * 2);
    ushort*   wt2    = (ushort*)take((size_t)256 * 128 * 2);
    ushort*   wt3    = (ushort*)take((size_t)128 * 64 * 2);
    (void)ws_size; (void)n_in; (void)in_sizes; (void)out_size;

    const int ZB = 256;
    const int egrid = (ETOT + ZB - 1) / ZB;
    const int mtiles = (NN + 63) / 64;       // 313
    const int algrid = (2 * NN * H + ZB - 1) / ZB;

    // zero: deg, fill, pooled+cnt
    zero_u32<<<(NN + ZB - 1) / ZB, ZB, 0, stream>>>((uint32_t*)deg, NN);
    zero_u32<<<(NN + ZB - 1) / ZB, ZB, 0, stream>>>((uint32_t*)fill, NN);
    zero_u32<<<2, ZB, 0, stream>>>((uint32_t*)pooled, BG * 32 + BG);

    // weight conversion (bf16, transposed; input weight K-padded 100->128)
    convW<FIN, 128, 256><<<(256 * 128 + 255) / 256, 256, 0, stream>>>(Wi, wti);
    convW<256, 256, 1024><<<(1024 * 256 + 255) / 256, 256, 0, stream>>>(Wl[0], wt0);
    convW<256, 256, 512><<<(512 * 256 + 255) / 256, 256, 0, stream>>>(Wl[1], wt1);
    convW<128, 128, 256><<<(256 * 128 + 255) / 256, 256, 0, stream>>>(Wl[2], wt2);
    convW<64, 64, 128><<<(128 * 64 + 255) / 256, 256, 0, stream>>>(Wl[3], wt3);
    convX<<<(NN * 128 + 255) / 256, 256, 0, stream>>>(x, xpad);

    // CSR by dst
    count_deg<<<egrid, ZB, 0, stream>>>(ei, deg);
    scan_kernel<<<1, 1024, 0, stream>>>(deg, rowptr);
    scatter_edges<<<egrid, ZB, 0, stream>>>(ei, rowptr, fill, esrc);

    const int sgrid = (NN * 64 + 255) / 256;  // softmax: 1 wave per dst

    // input layer: hAbf = relu(x @ Wi + bi)
    gemm_mfma<128, 256, true, false><<<dim3(mtiles, 4), 256, 0, stream>>>(
        xpad, wti, bi, hAbf, nullptr, nullptr, nullptr, nullptr, NN);

    // ---- level 0: 256 -> 256, residual ----
    zero_u32<<<algrid, ZB, 0, stream>>>((uint32_t*)al_s, 2 * NN * H);
    gemm_mfma<256, 1024, false, true><<<dim3(mtiles, 16), 256, 0, stream>>>(
        hAbf, wt0, nullptr, hproj, Asl[0], Adl[0], al_s, al_d, NN);
    softmax_csr<<<sgrid, 256, 0, stream>>>(rowptr, esrc, al_s, al_d, alpha);
    aggregate<256, true><<<NN, 256, 0, stream>>>(hproj, rowptr, esrc, alpha,
                                                 Bl[0], Gl[0], Bel[0], hAbf, hBbf);
    // ---- level 1: 256 -> 128 ----
    zero_u32<<<algrid, ZB, 0, stream>>>((uint32_t*)al_s, 2 * NN * H);
    gemm_mfma<256, 512, false, true><<<dim3(mtiles, 8), 256, 0, stream>>>(
        hBbf, wt1, nullptr, hproj, Asl[1], Adl[1], al_s, al_d, NN);
    softmax_csr<<<sgrid, 256, 0, stream>>>(rowptr, esrc, al_s, al_d, alpha);
    aggregate<128, false><<<NN, 256, 0, stream>>>(hproj, rowptr, esrc, alpha,
                                                  Bl[1], Gl[1], Bel[1], nullptr, hAbf);
    // ---- level 2: 128 -> 64 ----
    zero_u32<<<algrid, ZB, 0, stream>>>((uint32_t*)al_s, 2 * NN * H);
    gemm_mfma<128, 256, false, true><<<dim3(mtiles, 4), 256, 0, stream>>>(
        hAbf, wt2, nullptr, hproj, Asl[2], Adl[2], al_s, al_d, NN);
    softmax_csr<<<sgrid, 256, 0, stream>>>(rowptr, esrc, al_s, al_d, alpha);
    aggregate<64, false><<<NN, 256, 0, stream>>>(hproj, rowptr, esrc, alpha,
                                                 Bl[2], Gl[2], Bel[2], nullptr, hBbf);
    // ---- level 3: 64 -> 32 ----
    zero_u32<<<algrid, ZB, 0, stream>>>((uint32_t*)al_s, 2 * NN * H);
    gemm_mfma<64, 128, false, true><<<dim3(mtiles, 2), 256, 0, stream>>>(
        hBbf, wt3, nullptr, hproj, Asl[3], Adl[3], al_s, al_d, NN);
    softmax_csr<<<sgrid, 256, 0, stream>>>(rowptr, esrc, al_s, al_d, alpha);
    aggregate<32, false><<<NN, 256, 0, stream>>>(hproj, rowptr, esrc, alpha,
                                                 Bl[3], Gl[3], Bel[3], nullptr, hAbf);

    // ---- pooling + readout ----
    pool_accum2<<<80, 256, 0, stream>>>(hAbf, batch, pooled, cnt);
    final_out<<<1, 64, 0, stream>>>(pooled, cnt, Wo, bo, (float*)d_out);
}